// Round 11
// baseline (429.621 us; speedup 1.0000x reference)
//
#include <hip/hip_runtime.h>
#include <stdint.h>

#define N_NODES 50000
#define N_EDGES 800000
#define D_IN    128
#define D_HID   512
#define NPAD    50048   // 391 * 128
#define NTILES  391     // NPAD / 128
#define SCAN_NB 196     // ceil(50000/256)
#define G_TILES 782     // NPAD / 64
#define G_BLOCKS 256
#define H1_FULL_NEED 64797440LL   // 13548288 + NPAD*512*2
#define FILL_CH 2048              // edges per block chunk (256 thr x 8)
#define FILL_SUB ((N_EDGES + FILL_CH - 1) / FILL_CH)   // 391
#define NPH 8                     // gather src phases (slice = 12.8/8 = 1.6 MB bf16, L2-fits)

typedef __attribute__((ext_vector_type(8))) short short8;
typedef __attribute__((ext_vector_type(4))) float f32x4;

__device__ __forceinline__ float bf2f(unsigned short u) {
    union { unsigned int i; float f; } v; v.i = ((unsigned int)u) << 16; return v.f;
}
__device__ __forceinline__ unsigned short f2bf(float f) {
    union { float f; unsigned int i; } v; v.f = f;
    unsigned int r = v.i + 0x7fffu + ((v.i >> 16) & 1u);
    return (unsigned short)(r >> 16);
}
__device__ __forceinline__ float loadP(const void* p, long i, int isf) {
    return isf ? ((const float*)p)[i] : bf2f(((const unsigned short*)p)[i]);
}

// ---- fused: zero all stats(1408)+counts (blocks 0..200) + detect flags (block 201) ----
__global__ void k_init(const void* __restrict__ x, const int* __restrict__ ei,
                       float* __restrict__ stats, int* __restrict__ counts,
                       int* __restrict__ flags) {
    int t = threadIdx.x;
    if (blockIdx.x < 201) {
        int i = blockIdx.x * 256 + t;
        if (i < 1408) stats[i] = 0.f;                     // sum1|sumsq1|sum2|sumsq2|colsum
        else if (i < 1408 + N_NODES) counts[i - 1408] = 0;
    } else {
        __shared__ int sh[2];
        if (t == 0) { sh[0] = 0; sh[1] = 1; }
        __syncthreads();
        const unsigned short* xu = (const unsigned short*)x;
        for (int i = t; i < 8192; i += 256)
            if (((xu[i] >> 7) & 0xFF) == 0xFF) sh[0] = 1;   // benign race
        for (int k = t; k < 64; k += 256)
            if (ei[2 * k + 1] != 0) sh[1] = 0;
        __syncthreads();
        if (t == 0) { flags[0] = sh[0]; flags[1] = sh[1]; }
    }
}

// ---- merged: weight transposes (blocks 0..511) + in-degree count (blocks 512+) ----
// Both depend only on k_init; merging removes one serialized launch.
// Count is dst-range partitioned to XCDs (verified r10 mechanism).
__global__ __launch_bounds__(256) void k_prep(const void* __restrict__ W1, const void* __restrict__ W2,
                                              unsigned short* __restrict__ w1t, unsigned short* __restrict__ w2t,
                                              const int* __restrict__ ei, int* __restrict__ counts,
                                              const int* __restrict__ flags) {
    int isf = flags[0];
    if (blockIdx.x < 512) {
        int idx = blockIdx.x * 256 + threadIdx.x;     // 131072 threads
        if (idx < D_IN * D_HID) {
            int n = idx >> 7, k = idx & 127;          // w1t[n][k] = W1[k][n]
            int src = k * D_HID + n;
            w1t[idx] = isf ? f2bf(((const float*)W1)[src])
                           : ((const unsigned short*)W1)[src];
        } else {
            int j = idx - D_IN * D_HID;
            int n = j >> 9, k = j & 511;              // w2t[n][k] = W2[k][n]
            int src = k * D_IN + n;
            w2t[j] = isf ? f2bf(((const float*)W2)[src])
                         : ((const unsigned short*)W2)[src];
        }
    } else {
        int i64 = flags[1];
        int bid = blockIdx.x - 512;
        int gid = bid & 7;
        int sub = bid >> 3;
        int lo = gid * (N_NODES / 8), hi = lo + (N_NODES / 8);
        int base = sub * FILL_CH + threadIdx.x;
#pragma unroll
        for (int i = 0; i < 8; i++) {
            int e = base + i * 256;
            if (e < N_EDGES) {
                int d = i64 ? ei[2 * N_EDGES + 2 * e] : ei[N_EDGES + e];
                d = min(max(d, 0), N_NODES - 1);
                if (d >= lo && d < hi) atomicAdd(&counts[d], 1);
            }
        }
    }
}

// ---- CSR step 2a: per-block exclusive scan; block sums -> partials (raw) ----
__global__ __launch_bounds__(256) void k_scan_block(const int* __restrict__ counts,
                                                    int* __restrict__ rowptr,
                                                    int* __restrict__ partials) {
    __shared__ int a[256], b[256];
    int t = threadIdx.x;
    int idx = blockIdx.x * 256 + t;
    int c = (idx < N_NODES) ? counts[idx] : 0;
    a[t] = c;
    __syncthreads();
    int* src = a; int* dst = b;
    for (int off = 1; off < 256; off <<= 1) {
        dst[t] = src[t] + ((t >= off) ? src[t - off] : 0);
        __syncthreads();
        int* tmp = src; src = dst; dst = tmp;
    }
    if (idx < N_NODES) rowptr[idx] = src[t] - c;
    if (t == 255) partials[blockIdx.x] = src[255];
}

// ---- CSR step 2b+2c merged: per-block prefix reduce + add; mirror to cursor ----
__global__ __launch_bounds__(256) void k_scan_add(int* __restrict__ rowptr, int* __restrict__ cursor,
                                                  const int* __restrict__ partials) {
    __shared__ int red[256];
    int t = threadIdx.x, bid = blockIdx.x;
    red[t] = (t < SCAN_NB && t < bid) ? partials[t] : 0;
    __syncthreads();
#pragma unroll
    for (int off = 128; off > 0; off >>= 1) {
        if (t < off) red[t] += red[t + off];
        __syncthreads();
    }
    int prefix = red[0];
    int idx = bid * 256 + t;
    if (idx < N_NODES) {
        int v = rowptr[idx] + prefix;
        rowptr[idx] = v;
        cursor[idx] = v;
    } else if (idx == N_NODES) {
        rowptr[N_NODES] = N_EDGES;
    }
}

// ---- CSR step 3: fill buckets, dst-range partitioned to XCDs (verified r9) ----
__global__ __launch_bounds__(256) void k_fill(const int* __restrict__ ei, int* __restrict__ cursor,
                                              int* __restrict__ bucket, const int* __restrict__ flags) {
    int i64 = flags[1];
    int gid = blockIdx.x & 7;
    int sub = blockIdx.x >> 3;
    int lo = gid * (N_NODES / 8), hi = lo + (N_NODES / 8);   // 6250 each, exact
    int base = sub * FILL_CH + threadIdx.x;
#pragma unroll
    for (int i = 0; i < 8; i++) {
        int e = base + i * 256;
        if (e < N_EDGES) {
            int d = i64 ? ei[2 * N_EDGES + 2 * e] : ei[N_EDGES + e];
            d = min(max(d, 0), N_NODES - 1);
            if (d >= lo && d < hi) {
                int s = i64 ? ei[2 * e] : ei[e];
                s = min(max(s, 0), N_NODES - 1);
                int pos = atomicAdd(&cursor[d], 1);
                bucket[pos] = s;
            }
        }
    }
}

// ---- gather-sum, src-PHASED for L2 residency ----
// x (12.8 MB bf16) is 3x one XCD's 4 MB L2 -> random access misses L2 and runs
// at the ~3.6 TB/s L3 random ceiling (r9/r10: FETCH 184 MB = 90% of zero-reuse).
// Phase p touches only x rows in [p*6250,(p+1)*6250) = 1.6 MB -> L2-resident;
// bucket re-scan is wave-uniform (all 64 lanes share j) -> broadcast L1 hits.
__global__ __launch_bounds__(256) void k_gather(const int* __restrict__ rowptr,
                                                const int* __restrict__ bucket,
                                                const void* __restrict__ x,
                                                unsigned short* __restrict__ agg,
                                                const int* __restrict__ flags) {
    int isf = flags[0];
    int w = threadIdx.x >> 6, lane = threadIdx.x & 63;
    int row = blockIdx.x * 4 + w;          // grid = NPAD/4, exact
    float a0 = 0.f, a1 = 0.f;
    if (row < N_NODES) {
        int beg = rowptr[row], end = rowptr[row + 1];
        if (isf) {
            const float* xf = (const float*)x;
            float2 v = *(const float2*)(xf + (size_t)row * D_IN + lane * 2);
            a0 = v.x; a1 = v.y;
            for (int p = 0; p < NPH; p++) {
                int lo = p * (N_NODES / NPH), hi = lo + (N_NODES / NPH);
                int j = beg;
                for (; j + 4 <= end; j += 4) {
                    int s0 = bucket[j], s1 = bucket[j + 1], s2 = bucket[j + 2], s3 = bucket[j + 3];
                    if (s0 >= lo && s0 < hi) { float2 n = *(const float2*)(xf + (size_t)s0 * D_IN + lane * 2); a0 += n.x; a1 += n.y; }
                    if (s1 >= lo && s1 < hi) { float2 n = *(const float2*)(xf + (size_t)s1 * D_IN + lane * 2); a0 += n.x; a1 += n.y; }
                    if (s2 >= lo && s2 < hi) { float2 n = *(const float2*)(xf + (size_t)s2 * D_IN + lane * 2); a0 += n.x; a1 += n.y; }
                    if (s3 >= lo && s3 < hi) { float2 n = *(const float2*)(xf + (size_t)s3 * D_IN + lane * 2); a0 += n.x; a1 += n.y; }
                }
                for (; j < end; j++) {
                    int s = bucket[j];
                    if (s >= lo && s < hi) { float2 n = *(const float2*)(xf + (size_t)s * D_IN + lane * 2); a0 += n.x; a1 += n.y; }
                }
            }
        } else {
            const unsigned int* xu = (const unsigned int*)x;
            unsigned int u = xu[(size_t)row * 64 + lane];
            a0 = bf2f(u & 0xffff); a1 = bf2f(u >> 16);
            for (int p = 0; p < NPH; p++) {
                int lo = p * (N_NODES / NPH), hi = lo + (N_NODES / NPH);
                int j = beg;
                for (; j + 4 <= end; j += 4) {
                    int s0 = bucket[j], s1 = bucket[j + 1], s2 = bucket[j + 2], s3 = bucket[j + 3];
                    if (s0 >= lo && s0 < hi) { unsigned int n = xu[(size_t)s0 * 64 + lane]; a0 += bf2f(n & 0xffff); a1 += bf2f(n >> 16); }
                    if (s1 >= lo && s1 < hi) { unsigned int n = xu[(size_t)s1 * 64 + lane]; a0 += bf2f(n & 0xffff); a1 += bf2f(n >> 16); }
                    if (s2 >= lo && s2 < hi) { unsigned int n = xu[(size_t)s2 * 64 + lane]; a0 += bf2f(n & 0xffff); a1 += bf2f(n >> 16); }
                    if (s3 >= lo && s3 < hi) { unsigned int n = xu[(size_t)s3 * 64 + lane]; a0 += bf2f(n & 0xffff); a1 += bf2f(n >> 16); }
                }
                for (; j < end; j++) {
                    int s = bucket[j];
                    if (s >= lo && s < hi) { unsigned int n = xu[(size_t)s * 64 + lane]; a0 += bf2f(n & 0xffff); a1 += bf2f(n >> 16); }
                }
            }
        }
    }
    unsigned int o = (unsigned int)f2bf(a0) | ((unsigned int)f2bf(a1) << 16);
    ((unsigned int*)agg)[(size_t)row * 64 + lane] = o;
}

// ---- Gram: Gpart[b] = partial A^T A over this block's row tiles; colsum atomics ----
__global__ __launch_bounds__(256) void k_gram(const unsigned short* __restrict__ aggb,
                                              float* __restrict__ Gpart,
                                              float* __restrict__ colsum) {
    __shared__ unsigned short ldsT[128 * 64];   // [col][k], k-chunks XOR-swizzled, 16 KB
    int t = threadIdx.x;
    int wid = t >> 6, lane = t & 63;
    int wm = wid & 1, wn = wid >> 1;
    int quad = lane >> 4, l16 = lane & 15;
    f32x4 acc[4][4] = {};
    float cs = 0.f;
    int cscol = t & 127, cskh = t >> 7;
    for (int tile = blockIdx.x; tile < G_TILES; tile += G_BLOCKS) {
        __syncthreads();
        size_t rowbase = (size_t)tile * 64;
#pragma unroll
        for (int jj = 0; jj < 2; jj++) {
            int j = t + jj * 256;
            int c = j >> 5, rp = j & 31;          // cols c*8..+7, rows 2rp,2rp+1
            uint4 v0 = *(const uint4*)(aggb + (rowbase + 2 * rp) * 128 + c * 8);
            uint4 v1 = *(const uint4*)(aggb + (rowbase + 2 * rp + 1) * 128 + c * 8);
            const unsigned short* p0 = (const unsigned short*)&v0;
            const unsigned short* p1 = (const unsigned short*)&v1;
            int k = 2 * rp, kc = k >> 3, ko = k & 7;
#pragma unroll
            for (int e = 0; e < 8; e++) {
                int col = c * 8 + e;
                *(unsigned int*)(ldsT + col * 64 + ((kc ^ (col & 7)) * 8) + ko) =
                    (unsigned int)p0[e] | ((unsigned int)p1[e] << 16);
            }
        }
        __syncthreads();
#pragma unroll
        for (int ksub = 0; ksub < 2; ksub++) {
            short8 fa[4], fb[4];
#pragma unroll
            for (int mt = 0; mt < 4; mt++) {
                int col = wm * 64 + mt * 16 + l16;
                fa[mt] = *(const short8*)(ldsT + col * 64 + (((ksub * 4 + quad) ^ (col & 7)) * 8));
            }
#pragma unroll
            for (int nt = 0; nt < 4; nt++) {
                int col = wn * 64 + nt * 16 + l16;
                fb[nt] = *(const short8*)(ldsT + col * 64 + (((ksub * 4 + quad) ^ (col & 7)) * 8));
            }
#pragma unroll
            for (int mt = 0; mt < 4; mt++)
#pragma unroll
                for (int nt = 0; nt < 4; nt++)
                    acc[mt][nt] = __builtin_amdgcn_mfma_f32_16x16x32_bf16(fa[mt], fb[nt], acc[mt][nt], 0, 0, 0);
        }
        // colsum partial: thread handles (col, k-half)
#pragma unroll
        for (int kc = 0; kc < 4; kc++) {
            short8 v = *(const short8*)(ldsT + cscol * 64 + (((cskh * 4 + kc) ^ (cscol & 7)) * 8));
#pragma unroll
            for (int e = 0; e < 8; e++) cs += bf2f((unsigned short)v[e]);
        }
    }
    float* gp = Gpart + (size_t)blockIdx.x * 16384;
#pragma unroll
    for (int mt = 0; mt < 4; mt++)
#pragma unroll
        for (int nt = 0; nt < 4; nt++) {
            int m = wm * 64 + mt * 16 + quad * 4;
            int n = wn * 64 + nt * 16 + l16;
#pragma unroll
            for (int rg = 0; rg < 4; rg++)
                gp[(m + rg) * 128 + n] = acc[mt][nt][rg];
        }
    atomicAdd(&colsum[cscol], cs);
}

// ---- reduce Gpart -> G ----
__global__ void k_gred(const float* __restrict__ Gpart, float* __restrict__ G) {
    int i = blockIdx.x * 256 + threadIdx.x;     // 64 blocks -> 16384 threads
    float s = 0.f;
#pragma unroll 8
    for (int b = 0; b < G_BLOCKS; b++) s += Gpart[(size_t)b * 16384 + i];
    G[i] = s;
}

// ---- BN1 stats from Gram: sum1[n]=cs.w_n + N b; sumsq1[n]=w^T G w + 2b(cs.w) + N b^2 ----
__global__ __launch_bounds__(256) void k_bn1(const float* __restrict__ G,
                                             const float* __restrict__ colsum,
                                             const unsigned short* __restrict__ w1t,
                                             const void* __restrict__ b1,
                                             float* __restrict__ sum1,
                                             float* __restrict__ sumsq1,
                                             const int* __restrict__ flags) {
    int isf = flags[0];
    __shared__ float wsh[4][128];
    int t = threadIdx.x, wid = t >> 6, lane = t & 63;
    int n = blockIdx.x * 4 + wid;               // 128 blocks x 4 waves = 512 n
    unsigned int u = *(const unsigned int*)(w1t + (size_t)n * 128 + lane * 2);
    wsh[wid][lane * 2] = bf2f(u & 0xffff);
    wsh[wid][lane * 2 + 1] = bf2f(u >> 16);
    __syncthreads();
    const float* w = wsh[wid];
    const f32x4* g0 = (const f32x4*)(G + (size_t)lane * 128);
    const f32x4* g1 = (const f32x4*)(G + (size_t)(lane + 64) * 128);
    float t0 = 0.f, t1 = 0.f;
#pragma unroll 4
    for (int q4 = 0; q4 < 32; q4++) {
        f32x4 a = g0[q4], b = g1[q4];
        float w0 = w[q4 * 4], w1 = w[q4 * 4 + 1], w2 = w[q4 * 4 + 2], w3 = w[q4 * 4 + 3];
        t0 += a[0] * w0 + a[1] * w1 + a[2] * w2 + a[3] * w3;
        t1 += b[0] * w0 + b[1] * w1 + b[2] * w2 + b[3] * w3;
    }
    float sq = w[lane] * t0 + w[lane + 64] * t1;
    float s  = w[lane] * colsum[lane] + w[lane + 64] * colsum[lane + 64];
#pragma unroll
    for (int m = 1; m < 64; m <<= 1) {
        sq += __shfl_xor(sq, m, 64);
        s  += __shfl_xor(s, m, 64);
    }
    if (lane == 0) {
        float b = loadP(b1, n, isf);
        sum1[n]   = s + (float)N_NODES * b;
        sumsq1[n] = sq + 2.f * b * s + (float)N_NODES * b * b;
    }
}

// ---- MLP stage 1 (gram path, per chunk): h1c = relu(BN1(aggc @ W1 + b1)) ----
__global__ __launch_bounds__(256, 2) void k_mlp1(const unsigned short* __restrict__ aggc,
                                                 const unsigned short* __restrict__ w1t,
                                                 const void* __restrict__ b1,
                                                 const void* __restrict__ g1,
                                                 const void* __restrict__ bb1,
                                                 const float* __restrict__ sum1,
                                                 const float* __restrict__ sumsq1,
                                                 unsigned short* __restrict__ h1c,
                                                 const int* __restrict__ flags) {
    __shared__ unsigned short bufA[128 * 128];   // 32 KB: X tile, then output tile
    __shared__ unsigned short bufW[128 * 128];   // 32 KB: W1 tile
    int isf = flags[0];
    int t = threadIdx.x;
    int m0 = (blockIdx.x >> 2) * 128;            // chunk-relative row
    int nb = blockIdx.x & 3;
    int r = t >> 1, half = t & 1;
    int wid = t >> 6, lane = t & 63;
    int wm = wid & 1, wn = wid >> 1;
    int quad = lane >> 4, l16 = lane & 15;
#pragma unroll
    for (int i = 0; i < 8; i++) {
        int chunk = half * 8 + i;
        int sw = ((chunk ^ (r & 15)) * 8);
        *(uint4*)(bufA + r * 128 + sw) = *(const uint4*)(aggc + (size_t)(m0 + r) * 128 + chunk * 8);
        *(uint4*)(bufW + r * 128 + sw) = *(const uint4*)(w1t + (size_t)(nb * 128 + r) * 128 + chunk * 8);
    }
    __syncthreads();
    f32x4 acc[4][4] = {};
#pragma unroll
    for (int ks = 0; ks < 4; ks++) {
        short8 af[4], bw[4];
#pragma unroll
        for (int mt = 0; mt < 4; mt++)
            af[mt] = *(const short8*)(bufA + (wm * 64 + mt * 16 + l16) * 128 + (((ks * 4 + quad) ^ l16) * 8));
#pragma unroll
        for (int nt = 0; nt < 4; nt++)
            bw[nt] = *(const short8*)(bufW + (wn * 64 + nt * 16 + l16) * 128 + (((ks * 4 + quad) ^ l16) * 8));
#pragma unroll
        for (int mt = 0; mt < 4; mt++)
#pragma unroll
            for (int nt = 0; nt < 4; nt++)
                acc[mt][nt] = __builtin_amdgcn_mfma_f32_16x16x32_bf16(af[mt], bw[nt], acc[mt][nt], 0, 0, 0);
    }
    __syncthreads();   // all LDS reads done; bufA reused for output
#pragma unroll
    for (int nt = 0; nt < 4; nt++) {
        int nl = wn * 64 + nt * 16 + l16;
        int n1 = nb * 128 + nl;
        float mz = sum1[n1] * (1.f / N_NODES);
        float vz = sumsq1[n1] * (1.f / N_NODES) - mz * mz;
        float inv = rsqrtf(fmaxf(vz, 0.f) + 1e-5f);
        float A = loadP(g1, n1, isf) * inv;
        float C = loadP(bb1, n1, isf) - mz * A + loadP(b1, n1, isf) * A;
        int ccw = nl >> 3, cl = nl & 7;
#pragma unroll
        for (int mt = 0; mt < 4; mt++)
#pragma unroll
            for (int rg = 0; rg < 4; rg++) {
                int R = wm * 64 + mt * 16 + quad * 4 + rg;
                bufA[R * 128 + ((ccw ^ (R & 15)) * 8) + cl] = f2bf(fmaxf(acc[mt][nt][rg] * A + C, 0.f));
            }
    }
    __syncthreads();
#pragma unroll
    for (int i = 0; i < 8; i++) {
        int idx = t + i * 256;                   // 2048 uint4 = full 32 KB tile
        int rr = idx >> 4, chunk = idx & 15;
        *(uint4*)(h1c + (size_t)(m0 + rr) * D_HID + nb * 128 + chunk * 8) =
            *(const uint4*)(bufA + rr * 128 + ((chunk ^ (rr & 15)) * 8));
    }
}

// ---- MLP stage 1 (big-ws path): h1 = agg @ W1 + b1 RAW, BN1 stats fused ----
__global__ __launch_bounds__(256, 2) void k_mlp1r(const unsigned short* __restrict__ aggb,
                                                  const unsigned short* __restrict__ w1t,
                                                  const void* __restrict__ b1,
                                                  unsigned short* __restrict__ h1,
                                                  float* __restrict__ sum1,
                                                  float* __restrict__ sumsq1,
                                                  const int* __restrict__ flags) {
    __shared__ unsigned short bufA[128 * 128];
    __shared__ unsigned short bufW[128 * 128];
    __shared__ float sred[256];
    int isf = flags[0];
    int t = threadIdx.x;
    int m0 = (blockIdx.x >> 2) * 128;
    int nb = blockIdx.x & 3;
    int r = t >> 1, half = t & 1;
    int wid = t >> 6, lane = t & 63;
    int wm = wid & 1, wn = wid >> 1;
    int quad = lane >> 4, l16 = lane & 15;
    sred[t] = 0.f;
#pragma unroll
    for (int i = 0; i < 8; i++) {
        int chunk = half * 8 + i;
        int sw = ((chunk ^ (r & 15)) * 8);
        *(uint4*)(bufA + r * 128 + sw) = *(const uint4*)(aggb + (size_t)(m0 + r) * 128 + chunk * 8);
        *(uint4*)(bufW + r * 128 + sw) = *(const uint4*)(w1t + (size_t)(nb * 128 + r) * 128 + chunk * 8);
    }
    __syncthreads();
    f32x4 acc[4][4] = {};
#pragma unroll
    for (int ks = 0; ks < 4; ks++) {
        short8 af[4], bw[4];
#pragma unroll
        for (int mt = 0; mt < 4; mt++)
            af[mt] = *(const short8*)(bufA + (wm * 64 + mt * 16 + l16) * 128 + (((ks * 4 + quad) ^ l16) * 8));
#pragma unroll
        for (int nt = 0; nt < 4; nt++)
            bw[nt] = *(const short8*)(bufW + (wn * 64 + nt * 16 + l16) * 128 + (((ks * 4 + quad) ^ l16) * 8));
#pragma unroll
        for (int mt = 0; mt < 4; mt++)
#pragma unroll
            for (int nt = 0; nt < 4; nt++)
                acc[mt][nt] = __builtin_amdgcn_mfma_f32_16x16x32_bf16(af[mt], bw[nt], acc[mt][nt], 0, 0, 0);
    }
    __syncthreads();
    // epilogue: z = acc + b1 (raw), stats, bf16 -> bufA swizzled
#pragma unroll
    for (int nt = 0; nt < 4; nt++) {
        int nl = wn * 64 + nt * 16 + l16;
        int n1 = nb * 128 + nl;
        float bias = loadP(b1, n1, isf);
        int ccw = nl >> 3, cl = nl & 7;
        float s = 0.f, ss = 0.f;
#pragma unroll
        for (int mt = 0; mt < 4; mt++)
#pragma unroll
            for (int rg = 0; rg < 4; rg++) {
                int R = wm * 64 + mt * 16 + quad * 4 + rg;
                float z = acc[mt][nt][rg] + bias;
                bufA[R * 128 + ((ccw ^ (R & 15)) * 8) + cl] = f2bf(z);
                if (m0 + R < N_NODES) { s += z; ss += z * z; }
            }
        s += __shfl_xor(s, 16, 64); ss += __shfl_xor(ss, 16, 64);
        s += __shfl_xor(s, 32, 64); ss += __shfl_xor(ss, 32, 64);
        if (quad == 0) { atomicAdd(&sred[nl], s); atomicAdd(&sred[128 + nl], ss); }
    }
    __syncthreads();
#pragma unroll
    for (int i = 0; i < 8; i++) {
        int idx = t + i * 256;
        int rr = idx >> 4, chunk = idx & 15;
        *(uint4*)(h1 + (size_t)(m0 + rr) * D_HID + nb * 128 + chunk * 8) =
            *(const uint4*)(bufA + rr * 128 + ((chunk ^ (rr & 15)) * 8));
    }
    if (t < 128)      atomicAdd(&sum1[nb * 128 + t], sred[t]);
    else              atomicAdd(&sumsq1[nb * 128 + (t - 128)], sred[t]);
}

// ---- MLP stage 2 (gram path, per chunk): h2c = h1c @ W2 + b2, BN2 stats fused ----
__global__ __launch_bounds__(256, 3) void k_mlp2(const unsigned short* __restrict__ h1c,
                                                 const unsigned short* __restrict__ w2t,
                                                 const void* __restrict__ b2,
                                                 unsigned short* __restrict__ h2c,
                                                 float* __restrict__ sum2,
                                                 float* __restrict__ sumsq2,
                                                 const int* __restrict__ flags,
                                                 int roff) {
    __shared__ unsigned short bufA[64 * 128];
    __shared__ unsigned short bufW[128 * 128];
    __shared__ float sred[256];
    int isf = flags[0];
    int t = threadIdx.x;
    int m0 = blockIdx.x * 64;
    int rw = t >> 1, halfw = t & 1;
    int wid = t >> 6, lane = t & 63;
    int wm = wid & 1, wn = wid >> 1;
    int quad = lane >> 4, l16 = lane & 15;
    sred[t] = 0.f;
    f32x4 acc[2][4] = {};
    for (int kb = 0; kb < 4; kb++) {
        __syncthreads();
#pragma unroll
        for (int i = 0; i < 4; i++) {
            int idx = t + i * 256;
            int rr = idx >> 4, chunk = idx & 15;
            *(uint4*)(bufA + rr * 128 + ((chunk ^ (rr & 15)) * 8)) =
                *(const uint4*)(h1c + (size_t)(m0 + rr) * D_HID + kb * 128 + chunk * 8);
        }
#pragma unroll
        for (int i = 0; i < 8; i++) {
            int chunk = halfw * 8 + i;
            *(uint4*)(bufW + rw * 128 + ((chunk ^ (rw & 15)) * 8)) =
                *(const uint4*)(w2t + (size_t)rw * D_HID + kb * 128 + chunk * 8);
        }
        __syncthreads();
#pragma unroll
        for (int ks = 0; ks < 4; ks++) {
            short8 af[2], bw[4];
#pragma unroll
            for (int mt = 0; mt < 2; mt++)
                af[mt] = *(const short8*)(bufA + (wm * 32 + mt * 16 + l16) * 128 + (((ks * 4 + quad) ^ l16) * 8));
#pragma unroll
            for (int nt = 0; nt < 4; nt++)
                bw[nt] = *(const short8*)(bufW + (wn * 64 + nt * 16 + l16) * 128 + (((ks * 4 + quad) ^ l16) * 8));
#pragma unroll
            for (int mt = 0; mt < 2; mt++)
#pragma unroll
                for (int nt = 0; nt < 4; nt++)
                    acc[mt][nt] = __builtin_amdgcn_mfma_f32_16x16x32_bf16(af[mt], bw[nt], acc[mt][nt], 0, 0, 0);
        }
    }
    __syncthreads();
#pragma unroll
    for (int nt = 0; nt < 4; nt++) {
        int n = wn * 64 + nt * 16 + l16;
        float bias = loadP(b2, n, isf);
        float s = 0.f, ss = 0.f;
#pragma unroll
        for (int mt = 0; mt < 2; mt++) {
            int Rl = wm * 32 + mt * 16 + quad * 4;
#pragma unroll
            for (int rg = 0; rg < 4; rg++) {
                float z = acc[mt][nt][rg] + bias;
                bufW[(Rl + rg) * 128 + n] = f2bf(z);
                if (roff + m0 + Rl + rg < N_NODES) { s += z; ss += z * z; }
            }
        }
        s += __shfl_xor(s, 16, 64); ss += __shfl_xor(ss, 16, 64);
        s += __shfl_xor(s, 32, 64); ss += __shfl_xor(ss, 32, 64);
        if (quad == 0) { atomicAdd(&sred[n], s); atomicAdd(&sred[128 + n], ss); }
    }
    __syncthreads();
#pragma unroll
    for (int i = 0; i < 4; i++) {
        int idx = t + i * 256;
        int rr = idx >> 4, seg = idx & 15;
        *(uint4*)(h2c + (size_t)(m0 + rr) * D_IN + seg * 8) = *(const uint4*)(bufW + rr * 128 + seg * 8);
    }
    {
        int n = t & 127;
        if (t < 128) atomicAdd(&sum2[n], sred[n]);
        else         atomicAdd(&sumsq2[n], sred[128 + n]);
    }
}

// ---- MLP stage 2 (big-ws path): BM=128, 8 waves; BN1+ReLU on staging with
// vectorized coeff reads (chunk = t&15 is i-invariant) ----
__global__ __launch_bounds__(512, 4) void k_mlp2b(const unsigned short* __restrict__ h1,
                                                  const unsigned short* __restrict__ w2t,
                                                  const void* __restrict__ b2,
                                                  const void* __restrict__ g1,
                                                  const void* __restrict__ bb1,
                                                  const float* __restrict__ sum1,
                                                  const float* __restrict__ sumsq1,
                                                  unsigned short* __restrict__ h2,
                                                  float* __restrict__ sum2,
                                                  float* __restrict__ sumsq2,
                                                  const int* __restrict__ flags) {
    __shared__ unsigned short bufA[128 * 128];   // 32 KB: relu(BN1(h1)) K-slice
    __shared__ unsigned short bufW[128 * 128];   // 32 KB: w2t K-slice / h2 staging
    __shared__ float sred[256];
    __shared__ __align__(16) float bnA[512];
    __shared__ __align__(16) float bnC[512];
    int isf = flags[0];
    int t = threadIdx.x;
    int m0 = blockIdx.x * 128;
    int wid = t >> 6, lane = t & 63;
    int wm = wid & 3, wn = wid >> 2;             // 4 row-groups x 2 col-groups
    int quad = lane >> 4, l16 = lane & 15;
    int chunkT = t & 15;                         // i-invariant column chunk
    if (t < 256) sred[t] = 0.f;
    if (t < 512) {
        float mz = sum1[t] * (1.f / N_NODES);
        float vz = sumsq1[t] * (1.f / N_NODES) - mz * mz;
        float inv = rsqrtf(fmaxf(vz, 0.f) + 1e-5f);
        float A = loadP(g1, t, isf) * inv;
        bnA[t] = A;
        bnC[t] = loadP(bb1, t, isf) - mz * A;    // b1 already inside raw h1
    }
    f32x4 acc[2][4] = {};
    for (int kb = 0; kb < 4; kb++) {
        __syncthreads();   // first iter covers bnA/bnC/sred init; later: prev LDS reads done
        // per-thread BN coeffs for its 8 columns, vectorized (4 x ds_read_b128)
        f32x4 A0 = *(const f32x4*)(bnA + kb * 128 + chunkT * 8);
        f32x4 A1 = *(const f32x4*)(bnA + kb * 128 + chunkT * 8 + 4);
        f32x4 C0 = *(const f32x4*)(bnC + kb * 128 + chunkT * 8);
        f32x4 C1 = *(const f32x4*)(bnC + kb * 128 + chunkT * 8 + 4);
        // stage A: relu(BN1(h1)) rows m0..m0+127, cols kb*128..+128
#pragma unroll
        for (int i = 0; i < 4; i++) {
            int idx = t + i * 512;
            int rr = idx >> 4;
            uint4 v = *(const uint4*)(h1 + (size_t)(m0 + rr) * D_HID + kb * 128 + chunkT * 8);
            const unsigned short* pv = (const unsigned short*)&v;
            unsigned short o[8];
            o[0] = f2bf(fmaxf(bf2f(pv[0]) * A0[0] + C0[0], 0.f));
            o[1] = f2bf(fmaxf(bf2f(pv[1]) * A0[1] + C0[1], 0.f));
            o[2] = f2bf(fmaxf(bf2f(pv[2]) * A0[2] + C0[2], 0.f));
            o[3] = f2bf(fmaxf(bf2f(pv[3]) * A0[3] + C0[3], 0.f));
            o[4] = f2bf(fmaxf(bf2f(pv[4]) * A1[0] + C1[0], 0.f));
            o[5] = f2bf(fmaxf(bf2f(pv[5]) * A1[1] + C1[1], 0.f));
            o[6] = f2bf(fmaxf(bf2f(pv[6]) * A1[2] + C1[2], 0.f));
            o[7] = f2bf(fmaxf(bf2f(pv[7]) * A1[3] + C1[3], 0.f));
            *(uint4*)(bufA + rr * 128 + ((chunkT ^ (rr & 15)) * 8)) = *(const uint4*)o;
        }
        // stage W: w2t rows 0..127 (output cols), cols kb*128..+128
#pragma unroll
        for (int i = 0; i < 4; i++) {
            int idx = t + i * 512;
            int rr = idx >> 4;
            *(uint4*)(bufW + rr * 128 + ((chunkT ^ (rr & 15)) * 8)) =
                *(const uint4*)(w2t + (size_t)rr * D_HID + kb * 128 + chunkT * 8);
        }
        __syncthreads();
#pragma unroll
        for (int ks = 0; ks < 4; ks++) {
            short8 af[2], bw[4];
#pragma unroll
            for (int mt = 0; mt < 2; mt++)
                af[mt] = *(const short8*)(bufA + (wm * 32 + mt * 16 + l16) * 128 + (((ks * 4 + quad) ^ l16) * 8));
#pragma unroll
            for (int nt = 0; nt < 4; nt++)
                bw[nt] = *(const short8*)(bufW + (wn * 64 + nt * 16 + l16) * 128 + (((ks * 4 + quad) ^ l16) * 8));
#pragma unroll
            for (int mt = 0; mt < 2; mt++)
#pragma unroll
                for (int nt = 0; nt < 4; nt++)
                    acc[mt][nt] = __builtin_amdgcn_mfma_f32_16x16x32_bf16(af[mt], bw[nt], acc[mt][nt], 0, 0, 0);
        }
    }
    __syncthreads();       // last LDS reads done; bufW reused for h2 staging
    // epilogue: +b2, BN2 stats (LDS pre-reduce), h2 tile staged row-major
#pragma unroll
    for (int nt = 0; nt < 4; nt++) {
        int n = wn * 64 + nt * 16 + l16;
        float bias = loadP(b2, n, isf);
        float s = 0.f, ss = 0.f;
#pragma unroll
        for (int mt = 0; mt < 2; mt++) {
            int Rl = wm * 32 + mt * 16 + quad * 4;
#pragma unroll
            for (int rg = 0; rg < 4; rg++) {
                float z = acc[mt][nt][rg] + bias;
                bufW[(Rl + rg) * 128 + n] = f2bf(z);
                if (m0 + Rl + rg < N_NODES) { s += z; ss += z * z; }
            }
        }
        s += __shfl_xor(s, 16, 64); ss += __shfl_xor(ss, 16, 64);
        s += __shfl_xor(s, 32, 64); ss += __shfl_xor(ss, 32, 64);
        if (quad == 0) { atomicAdd(&sred[n], s); atomicAdd(&sred[128 + n], ss); }
    }
    __syncthreads();
#pragma unroll
    for (int i = 0; i < 4; i++) {
        int idx = t + i * 512;                   // 2048 uint4 = 32 KB (128x128 tile)
        int rr = idx >> 4, seg = idx & 15;
        *(uint4*)(h2 + (size_t)(m0 + rr) * D_IN + seg * 8) = *(const uint4*)(bufW + rr * 128 + seg * 8);
    }
    if (t < 256) {
        int n = t & 127;
        if (t < 128) atomicAdd(&sum2[n], sred[n]);
        else         atomicAdd(&sumsq2[n], sred[128 + n]);
    }
}

// ---- BN2 + ReLU + residual + LayerNorm -> out (h2 bf16 input) ----
__global__ __launch_bounds__(256) void k_final(const unsigned short* __restrict__ h2,
                                               const void* __restrict__ x,
                                               const float* __restrict__ sum2,
                                               const float* __restrict__ sumsq2,
                                               const void* __restrict__ g2,
                                               const void* __restrict__ bb2,
                                               const void* __restrict__ lng,
                                               const void* __restrict__ lnb,
                                               void* __restrict__ out,
                                               const int* __restrict__ flags) {
    int isf = flags[0];
    __shared__ float a2s[D_IN], c2s[D_IN];
    int t = threadIdx.x;
    if (t < D_IN) {
        float m = sum2[t] * (1.f / N_NODES);
        float v = sumsq2[t] * (1.f / N_NODES) - m * m;
        float inv = rsqrtf(fmaxf(v, 0.f) + 1e-5f);
        float a = loadP(g2, t, isf) * inv;
        a2s[t] = a;
        c2s[t] = loadP(bb2, t, isf) - m * a;
    }
    __syncthreads();
    int w = t >> 6, lane = t & 63;
    int row = blockIdx.x * 4 + w;
    if (row >= N_NODES) return;
    size_t base = (size_t)row * D_IN;
    int c0 = lane * 2, c1 = lane * 2 + 1;
    unsigned int hu = ((const unsigned int*)h2)[base / 2 + lane];
    float x0, x1;
    if (isf) {
        float2 xv = *((const float2*)x + base / 2 + lane);
        x0 = xv.x; x1 = xv.y;
    } else {
        unsigned int xu = ((const unsigned int*)x)[base / 2 + lane];
        x0 = bf2f(xu & 0xffff); x1 = bf2f(xu >> 16);
    }
    float o0 = fmaxf(a2s[c0] * bf2f(hu & 0xffff) + c2s[c0], 0.f) + x0;
    float o1 = fmaxf(a2s[c1] * bf2f(hu >> 16) + c2s[c1], 0.f) + x1;
    float s = o0 + o1, ss = o0 * o0 + o1 * o1;
#pragma unroll
    for (int m = 1; m < 64; m <<= 1) {
        s += __shfl_xor(s, m, 64);
        ss += __shfl_xor(ss, m, 64);
    }
    float mean = s * (1.f / D_IN);
    float var = ss * (1.f / D_IN) - mean * mean;
    float inv = rsqrtf(fmaxf(var, 0.f) + 1e-5f);
    float r0 = (o0 - mean) * inv * loadP(lng, c0, isf) + loadP(lnb, c0, isf);
    float r1 = (o1 - mean) * inv * loadP(lng, c1, isf) + loadP(lnb, c1, isf);
    if (isf) {
        *((float2*)out + base / 2 + lane) = make_float2(r0, r1);
    } else {
        ((unsigned int*)out)[base / 2 + lane] = (unsigned int)f2bf(r0) | ((unsigned int)f2bf(r1) << 16);
    }
}

extern "C" void kernel_launch(void* const* d_in, const int* in_sizes, int n_in,
                              void* d_out, int out_size, void* d_ws, size_t ws_size,
                              hipStream_t stream) {
    const void* x    = d_in[0];
    const int*  ei   = (const int*)d_in[1];
    const void* W1   = d_in[2];
    const void* b1   = d_in[3];
    const void* bn1g = d_in[4];
    const void* bn1b = d_in[5];
    const void* W2   = d_in[6];
    const void* b2   = d_in[7];
    const void* bn2g = d_in[8];
    const void* bn2b = d_in[9];
    const void* lng  = d_in[10];
    const void* lnb  = d_in[11];

    // workspace: phase A peaks at 33.53 MB; big-ws path (h1 full) needs 64.8 MB.
    char* ws = (char*)d_ws;
    float* stats   = (float*)ws;                      // 1408 f32
    float* sum1    = stats;
    float* sumsq1  = stats + 512;
    float* sum2    = stats + 1024;
    float* sumsq2  = stats + 1152;
    float* colsum  = stats + 1280;
    int*   flags   = (int*)(ws + 5632);
    int*   partials= (int*)(ws + 5696);
    int*   rowptr  = (int*)(ws + 8192);               // 50001 ints
    int*   cursor  = (int*)(ws + 208256);             // 50000 ints
    unsigned short* w1t = (unsigned short*)(ws + 408320);   // [512][128] bf16
    unsigned short* w2t = (unsigned short*)(ws + 539392);   // [128][512] bf16
    float* G       = (float*)(ws + 670464);           // 128x128 f32 -> ends 736000
    unsigned short* agg = (unsigned short*)(ws + 736000);   // NPAD*128 bf16 -> ends 13548288; reused as h2
    unsigned short* h2  = agg;
    int*   bucket  = (int*)(ws + 13548288);           // 800000 ints (dead after gather)
    float* Gpart   = (float*)(ws + 16748288);         // 256 x 16384 f32 (16 MB) -> ends 33525504
    unsigned short* h1r = (unsigned short*)(ws + 13548288); // overlays bucket+Gpart

    k_init<<<202, 256, 0, stream>>>(x, ei, stats, cursor, flags);
    k_prep<<<512 + 8 * FILL_SUB, 256, 0, stream>>>(W1, W2, w1t, w2t, ei, cursor, flags);
    k_scan_block<<<SCAN_NB, 256, 0, stream>>>(cursor, rowptr, partials);
    k_scan_add<<<SCAN_NB, 256, 0, stream>>>(rowptr, cursor, partials);
    k_fill<<<8 * FILL_SUB, 256, 0, stream>>>(ei, cursor, bucket, flags);
    k_gather<<<NPAD / 4, 256, 0, stream>>>(rowptr, bucket, x, agg, flags);

    if ((long long)ws_size >= H1_FULL_NEED) {
        // big-ws path: raw h1 + fused BN1 stats; no gram/gred/bn1; single pass
        k_mlp1r<<<NTILES * 4, 256, 0, stream>>>(agg, w1t, b1, h1r, sum1, sumsq1, flags);
        k_mlp2b<<<NTILES, 512, 0, stream>>>(h1r, w2t, b2, bn1g, bn1b, sum1, sumsq1,
                                            h2, sum2, sumsq2, flags);
    } else {
        k_gram<<<G_BLOCKS, 256, 0, stream>>>(agg, Gpart, colsum);
        k_gred<<<64, 256, 0, stream>>>(Gpart, G);
        k_bn1<<<128, 256, 0, stream>>>(G, colsum, w1t, b1, sum1, sumsq1, flags);
        long long avail = (long long)ws_size - 13548288LL;
        int max_tiles = (avail > 0) ? (int)(avail / 131072LL) : 1;
        if (max_tiles < 1)  max_tiles = 1;
        if (max_tiles > NTILES) max_tiles = NTILES;
        int nch = (NTILES + max_tiles - 1) / max_tiles;
        int per = (NTILES + nch - 1) / nch;
        for (int done = 0; done < NTILES; done += per) {
            int nt = NTILES - done;
            if (nt > per) nt = per;
            const unsigned short* aggc = agg + (size_t)done * 128 * 128;
            unsigned short* h2c = h2 + (size_t)done * 128 * 128;
            k_mlp1<<<nt * 4, 256, 0, stream>>>(aggc, w1t, b1, bn1g, bn1b, sum1, sumsq1, h1r, flags);
            k_mlp2<<<nt * 2, 256, 0, stream>>>(h1r, w2t, b2, h2c, sum2, sumsq2, flags, done * 128);
        }
    }

    k_final<<<(N_NODES + 3) / 4, 256, 0, stream>>>(h2, x, sum2, sumsq2, bn2g, bn2b, lng, lnb, d_out, flags);
}

// Round 12
// 324.484 us; speedup vs baseline: 1.3240x; 1.3240x over previous
//
#include <hip/hip_runtime.h>
#include <stdint.h>

#define N_NODES 50000
#define N_EDGES 800000
#define D_IN    128
#define D_HID   512
#define NPAD    50048   // 391 * 128
#define NTILES  391     // NPAD / 128
#define SCAN_NB 196     // ceil(50000/256)
#define G_TILES 782     // NPAD / 64
#define G_BLOCKS 256
#define H1_FULL_NEED 64797440LL   // 13548288 + NPAD*512*2
#define FILL_CH 2048              // edges per block chunk (256 thr x 8)
#define FILL_SUB ((N_EDGES + FILL_CH - 1) / FILL_CH)   // 391

typedef __attribute__((ext_vector_type(8))) short short8;
typedef __attribute__((ext_vector_type(4))) float f32x4;

__device__ __forceinline__ float bf2f(unsigned short u) {
    union { unsigned int i; float f; } v; v.i = ((unsigned int)u) << 16; return v.f;
}
__device__ __forceinline__ unsigned short f2bf(float f) {
    union { float f; unsigned int i; } v; v.f = f;
    unsigned int r = v.i + 0x7fffu + ((v.i >> 16) & 1u);
    return (unsigned short)(r >> 16);
}
__device__ __forceinline__ float loadP(const void* p, long i, int isf) {
    return isf ? ((const float*)p)[i] : bf2f(((const unsigned short*)p)[i]);
}

// ---- fused: zero all stats(1408)+counts (blocks 0..200) + detect flags (block 201) ----
__global__ void k_init(const void* __restrict__ x, const int* __restrict__ ei,
                       float* __restrict__ stats, int* __restrict__ counts,
                       int* __restrict__ flags) {
    int t = threadIdx.x;
    if (blockIdx.x < 201) {
        int i = blockIdx.x * 256 + t;
        if (i < 1408) stats[i] = 0.f;                     // sum1|sumsq1|sum2|sumsq2|colsum
        else if (i < 1408 + N_NODES) counts[i - 1408] = 0;
    } else {
        __shared__ int sh[2];
        if (t == 0) { sh[0] = 0; sh[1] = 1; }
        __syncthreads();
        const unsigned short* xu = (const unsigned short*)x;
        for (int i = t; i < 8192; i += 256)
            if (((xu[i] >> 7) & 0xFF) == 0xFF) sh[0] = 1;   // benign race
        for (int k = t; k < 64; k += 256)
            if (ei[2 * k + 1] != 0) sh[1] = 0;
        __syncthreads();
        if (t == 0) { flags[0] = sh[0]; flags[1] = sh[1]; }
    }
}

// ---- merged: weight transposes (blocks 0..511) + in-degree count (blocks 512+) ----
__global__ __launch_bounds__(256) void k_prep(const void* __restrict__ W1, const void* __restrict__ W2,
                                              unsigned short* __restrict__ w1t, unsigned short* __restrict__ w2t,
                                              const int* __restrict__ ei, int* __restrict__ counts,
                                              const int* __restrict__ flags) {
    int isf = flags[0];
    if (blockIdx.x < 512) {
        int idx = blockIdx.x * 256 + threadIdx.x;     // 131072 threads
        if (idx < D_IN * D_HID) {
            int n = idx >> 7, k = idx & 127;          // w1t[n][k] = W1[k][n]
            int src = k * D_HID + n;
            w1t[idx] = isf ? f2bf(((const float*)W1)[src])
                           : ((const unsigned short*)W1)[src];
        } else {
            int j = idx - D_IN * D_HID;
            int n = j >> 9, k = j & 511;              // w2t[n][k] = W2[k][n]
            int src = k * D_IN + n;
            w2t[j] = isf ? f2bf(((const float*)W2)[src])
                         : ((const unsigned short*)W2)[src];
        }
    } else {
        int i64 = flags[1];
        int bid = blockIdx.x - 512;
        int gid = bid & 7;
        int sub = bid >> 3;
        int lo = gid * (N_NODES / 8), hi = lo + (N_NODES / 8);
        int base = sub * FILL_CH + threadIdx.x;
#pragma unroll
        for (int i = 0; i < 8; i++) {
            int e = base + i * 256;
            if (e < N_EDGES) {
                int d = i64 ? ei[2 * N_EDGES + 2 * e] : ei[N_EDGES + e];
                d = min(max(d, 0), N_NODES - 1);
                if (d >= lo && d < hi) atomicAdd(&counts[d], 1);
            }
        }
    }
}

// ---- CSR step 2a: per-block exclusive scan; block sums -> partials (raw) ----
__global__ __launch_bounds__(256) void k_scan_block(const int* __restrict__ counts,
                                                    int* __restrict__ rowptr,
                                                    int* __restrict__ partials) {
    __shared__ int a[256], b[256];
    int t = threadIdx.x;
    int idx = blockIdx.x * 256 + t;
    int c = (idx < N_NODES) ? counts[idx] : 0;
    a[t] = c;
    __syncthreads();
    int* src = a; int* dst = b;
    for (int off = 1; off < 256; off <<= 1) {
        dst[t] = src[t] + ((t >= off) ? src[t - off] : 0);
        __syncthreads();
        int* tmp = src; src = dst; dst = tmp;
    }
    if (idx < N_NODES) rowptr[idx] = src[t] - c;
    if (t == 255) partials[blockIdx.x] = src[255];
}

// ---- CSR step 2b+2c merged: per-block prefix reduce + add; mirror to cursor ----
__global__ __launch_bounds__(256) void k_scan_add(int* __restrict__ rowptr, int* __restrict__ cursor,
                                                  const int* __restrict__ partials) {
    __shared__ int red[256];
    int t = threadIdx.x, bid = blockIdx.x;
    red[t] = (t < SCAN_NB && t < bid) ? partials[t] : 0;
    __syncthreads();
#pragma unroll
    for (int off = 128; off > 0; off >>= 1) {
        if (t < off) red[t] += red[t + off];
        __syncthreads();
    }
    int prefix = red[0];
    int idx = bid * 256 + t;
    if (idx < N_NODES) {
        int v = rowptr[idx] + prefix;
        rowptr[idx] = v;
        cursor[idx] = v;
    } else if (idx == N_NODES) {
        rowptr[N_NODES] = N_EDGES;
    }
}

// ---- CSR step 3: fill buckets, dst-range partitioned to XCDs (verified r9) ----
__global__ __launch_bounds__(256) void k_fill(const int* __restrict__ ei, int* __restrict__ cursor,
                                              int* __restrict__ bucket, const int* __restrict__ flags) {
    int i64 = flags[1];
    int gid = blockIdx.x & 7;
    int sub = blockIdx.x >> 3;
    int lo = gid * (N_NODES / 8), hi = lo + (N_NODES / 8);   // 6250 each, exact
    int base = sub * FILL_CH + threadIdx.x;
#pragma unroll
    for (int i = 0; i < 8; i++) {
        int e = base + i * 256;
        if (e < N_EDGES) {
            int d = i64 ? ei[2 * N_EDGES + 2 * e] : ei[N_EDGES + e];
            d = min(max(d, 0), N_NODES - 1);
            if (d >= lo && d < hi) {
                int s = i64 ? ei[2 * e] : ei[e];
                s = min(max(s, 0), N_NODES - 1);
                int pos = atomicAdd(&cursor[d], 1);
                bucket[pos] = s;
            }
        }
    }
}

// ---- gather-sum, 8-way ILP (round-10 version; phasing falsified in r11) ----
// 184 MB random fetch at ~3.6 TB/s L3 random-service rate = the measured floor.
__global__ __launch_bounds__(256) void k_gather(const int* __restrict__ rowptr,
                                                const int* __restrict__ bucket,
                                                const void* __restrict__ x,
                                                unsigned short* __restrict__ agg,
                                                const int* __restrict__ flags) {
    int isf = flags[0];
    int w = threadIdx.x >> 6, lane = threadIdx.x & 63;
    int row = blockIdx.x * 4 + w;          // grid = NPAD/4, exact
    float a0 = 0.f, a1 = 0.f;
    if (row < N_NODES) {
        int beg = rowptr[row], end = rowptr[row + 1];
        if (isf) {
            const float* xf = (const float*)x;
            float2 v = *(const float2*)(xf + (size_t)row * D_IN + lane * 2);
            a0 = v.x; a1 = v.y;
            int j = beg;
            for (; j + 8 <= end; j += 8) {
                float2 n0 = *(const float2*)(xf + (size_t)bucket[j] * D_IN + lane * 2);
                float2 n1 = *(const float2*)(xf + (size_t)bucket[j + 1] * D_IN + lane * 2);
                float2 n2 = *(const float2*)(xf + (size_t)bucket[j + 2] * D_IN + lane * 2);
                float2 n3 = *(const float2*)(xf + (size_t)bucket[j + 3] * D_IN + lane * 2);
                float2 n4 = *(const float2*)(xf + (size_t)bucket[j + 4] * D_IN + lane * 2);
                float2 n5 = *(const float2*)(xf + (size_t)bucket[j + 5] * D_IN + lane * 2);
                float2 n6 = *(const float2*)(xf + (size_t)bucket[j + 6] * D_IN + lane * 2);
                float2 n7 = *(const float2*)(xf + (size_t)bucket[j + 7] * D_IN + lane * 2);
                a0 += ((n0.x + n1.x) + (n2.x + n3.x)) + ((n4.x + n5.x) + (n6.x + n7.x));
                a1 += ((n0.y + n1.y) + (n2.y + n3.y)) + ((n4.y + n5.y) + (n6.y + n7.y));
            }
            for (; j + 4 <= end; j += 4) {
                float2 n0 = *(const float2*)(xf + (size_t)bucket[j] * D_IN + lane * 2);
                float2 n1 = *(const float2*)(xf + (size_t)bucket[j + 1] * D_IN + lane * 2);
                float2 n2 = *(const float2*)(xf + (size_t)bucket[j + 2] * D_IN + lane * 2);
                float2 n3 = *(const float2*)(xf + (size_t)bucket[j + 3] * D_IN + lane * 2);
                a0 += (n0.x + n1.x) + (n2.x + n3.x);
                a1 += (n0.y + n1.y) + (n2.y + n3.y);
            }
            for (; j < end; j++) {
                float2 n = *(const float2*)(xf + (size_t)bucket[j] * D_IN + lane * 2);
                a0 += n.x; a1 += n.y;
            }
        } else {
            const unsigned int* xu = (const unsigned int*)x;
            unsigned int u = xu[(size_t)row * 64 + lane];
            a0 = bf2f(u & 0xffff); a1 = bf2f(u >> 16);
            int j = beg;
            for (; j + 8 <= end; j += 8) {
                unsigned int u0 = xu[(size_t)bucket[j] * 64 + lane];
                unsigned int u1 = xu[(size_t)bucket[j + 1] * 64 + lane];
                unsigned int u2 = xu[(size_t)bucket[j + 2] * 64 + lane];
                unsigned int u3 = xu[(size_t)bucket[j + 3] * 64 + lane];
                unsigned int u4 = xu[(size_t)bucket[j + 4] * 64 + lane];
                unsigned int u5 = xu[(size_t)bucket[j + 5] * 64 + lane];
                unsigned int u6 = xu[(size_t)bucket[j + 6] * 64 + lane];
                unsigned int u7 = xu[(size_t)bucket[j + 7] * 64 + lane];
                a0 += ((bf2f(u0 & 0xffff) + bf2f(u1 & 0xffff)) + (bf2f(u2 & 0xffff) + bf2f(u3 & 0xffff)))
                    + ((bf2f(u4 & 0xffff) + bf2f(u5 & 0xffff)) + (bf2f(u6 & 0xffff) + bf2f(u7 & 0xffff)));
                a1 += ((bf2f(u0 >> 16) + bf2f(u1 >> 16)) + (bf2f(u2 >> 16) + bf2f(u3 >> 16)))
                    + ((bf2f(u4 >> 16) + bf2f(u5 >> 16)) + (bf2f(u6 >> 16) + bf2f(u7 >> 16)));
            }
            for (; j + 4 <= end; j += 4) {
                unsigned int u0 = xu[(size_t)bucket[j] * 64 + lane];
                unsigned int u1 = xu[(size_t)bucket[j + 1] * 64 + lane];
                unsigned int u2 = xu[(size_t)bucket[j + 2] * 64 + lane];
                unsigned int u3 = xu[(size_t)bucket[j + 3] * 64 + lane];
                a0 += (bf2f(u0 & 0xffff) + bf2f(u1 & 0xffff)) + (bf2f(u2 & 0xffff) + bf2f(u3 & 0xffff));
                a1 += (bf2f(u0 >> 16) + bf2f(u1 >> 16)) + (bf2f(u2 >> 16) + bf2f(u3 >> 16));
            }
            for (; j < end; j++) {
                unsigned int n = xu[(size_t)bucket[j] * 64 + lane];
                a0 += bf2f(n & 0xffff); a1 += bf2f(n >> 16);
            }
        }
    }
    unsigned int o = (unsigned int)f2bf(a0) | ((unsigned int)f2bf(a1) << 16);
    ((unsigned int*)agg)[(size_t)row * 64 + lane] = o;
}

// ---- Gram: Gpart[b] = partial A^T A over this block's row tiles; colsum atomics ----
__global__ __launch_bounds__(256) void k_gram(const unsigned short* __restrict__ aggb,
                                              float* __restrict__ Gpart,
                                              float* __restrict__ colsum) {
    __shared__ unsigned short ldsT[128 * 64];   // [col][k], k-chunks XOR-swizzled, 16 KB
    int t = threadIdx.x;
    int wid = t >> 6, lane = t & 63;
    int wm = wid & 1, wn = wid >> 1;
    int quad = lane >> 4, l16 = lane & 15;
    f32x4 acc[4][4] = {};
    float cs = 0.f;
    int cscol = t & 127, cskh = t >> 7;
    for (int tile = blockIdx.x; tile < G_TILES; tile += G_BLOCKS) {
        __syncthreads();
        size_t rowbase = (size_t)tile * 64;
#pragma unroll
        for (int jj = 0; jj < 2; jj++) {
            int j = t + jj * 256;
            int c = j >> 5, rp = j & 31;          // cols c*8..+7, rows 2rp,2rp+1
            uint4 v0 = *(const uint4*)(aggb + (rowbase + 2 * rp) * 128 + c * 8);
            uint4 v1 = *(const uint4*)(aggb + (rowbase + 2 * rp + 1) * 128 + c * 8);
            const unsigned short* p0 = (const unsigned short*)&v0;
            const unsigned short* p1 = (const unsigned short*)&v1;
            int k = 2 * rp, kc = k >> 3, ko = k & 7;
#pragma unroll
            for (int e = 0; e < 8; e++) {
                int col = c * 8 + e;
                *(unsigned int*)(ldsT + col * 64 + ((kc ^ (col & 7)) * 8) + ko) =
                    (unsigned int)p0[e] | ((unsigned int)p1[e] << 16);
            }
        }
        __syncthreads();
#pragma unroll
        for (int ksub = 0; ksub < 2; ksub++) {
            short8 fa[4], fb[4];
#pragma unroll
            for (int mt = 0; mt < 4; mt++) {
                int col = wm * 64 + mt * 16 + l16;
                fa[mt] = *(const short8*)(ldsT + col * 64 + (((ksub * 4 + quad) ^ (col & 7)) * 8));
            }
#pragma unroll
            for (int nt = 0; nt < 4; nt++) {
                int col = wn * 64 + nt * 16 + l16;
                fb[nt] = *(const short8*)(ldsT + col * 64 + (((ksub * 4 + quad) ^ (col & 7)) * 8));
            }
#pragma unroll
            for (int mt = 0; mt < 4; mt++)
#pragma unroll
                for (int nt = 0; nt < 4; nt++)
                    acc[mt][nt] = __builtin_amdgcn_mfma_f32_16x16x32_bf16(fa[mt], fb[nt], acc[mt][nt], 0, 0, 0);
        }
        // colsum partial: thread handles (col, k-half)
#pragma unroll
        for (int kc = 0; kc < 4; kc++) {
            short8 v = *(const short8*)(ldsT + cscol * 64 + (((cskh * 4 + kc) ^ (cscol & 7)) * 8));
#pragma unroll
            for (int e = 0; e < 8; e++) cs += bf2f((unsigned short)v[e]);
        }
    }
    float* gp = Gpart + (size_t)blockIdx.x * 16384;
#pragma unroll
    for (int mt = 0; mt < 4; mt++)
#pragma unroll
        for (int nt = 0; nt < 4; nt++) {
            int m = wm * 64 + mt * 16 + quad * 4;
            int n = wn * 64 + nt * 16 + l16;
#pragma unroll
            for (int rg = 0; rg < 4; rg++)
                gp[(m + rg) * 128 + n] = acc[mt][nt][rg];
        }
    atomicAdd(&colsum[cscol], cs);
}

// ---- reduce Gpart -> G ----
__global__ void k_gred(const float* __restrict__ Gpart, float* __restrict__ G) {
    int i = blockIdx.x * 256 + threadIdx.x;     // 64 blocks -> 16384 threads
    float s = 0.f;
#pragma unroll 8
    for (int b = 0; b < G_BLOCKS; b++) s += Gpart[(size_t)b * 16384 + i];
    G[i] = s;
}

// ---- BN1 stats from Gram: sum1[n]=cs.w_n + N b; sumsq1[n]=w^T G w + 2b(cs.w) + N b^2 ----
__global__ __launch_bounds__(256) void k_bn1(const float* __restrict__ G,
                                             const float* __restrict__ colsum,
                                             const unsigned short* __restrict__ w1t,
                                             const void* __restrict__ b1,
                                             float* __restrict__ sum1,
                                             float* __restrict__ sumsq1,
                                             const int* __restrict__ flags) {
    int isf = flags[0];
    __shared__ float wsh[4][128];
    int t = threadIdx.x, wid = t >> 6, lane = t & 63;
    int n = blockIdx.x * 4 + wid;               // 128 blocks x 4 waves = 512 n
    unsigned int u = *(const unsigned int*)(w1t + (size_t)n * 128 + lane * 2);
    wsh[wid][lane * 2] = bf2f(u & 0xffff);
    wsh[wid][lane * 2 + 1] = bf2f(u >> 16);
    __syncthreads();
    const float* w = wsh[wid];
    const f32x4* g0 = (const f32x4*)(G + (size_t)lane * 128);
    const f32x4* g1 = (const f32x4*)(G + (size_t)(lane + 64) * 128);
    float t0 = 0.f, t1 = 0.f;
#pragma unroll 4
    for (int q4 = 0; q4 < 32; q4++) {
        f32x4 a = g0[q4], b = g1[q4];
        float w0 = w[q4 * 4], w1 = w[q4 * 4 + 1], w2 = w[q4 * 4 + 2], w3 = w[q4 * 4 + 3];
        t0 += a[0] * w0 + a[1] * w1 + a[2] * w2 + a[3] * w3;
        t1 += b[0] * w0 + b[1] * w1 + b[2] * w2 + b[3] * w3;
    }
    float sq = w[lane] * t0 + w[lane + 64] * t1;
    float s  = w[lane] * colsum[lane] + w[lane + 64] * colsum[lane + 64];
#pragma unroll
    for (int m = 1; m < 64; m <<= 1) {
        sq += __shfl_xor(sq, m, 64);
        s  += __shfl_xor(s, m, 64);
    }
    if (lane == 0) {
        float b = loadP(b1, n, isf);
        sum1[n]   = s + (float)N_NODES * b;
        sumsq1[n] = sq + 2.f * b * s + (float)N_NODES * b * b;
    }
}

// ---- MLP stage 1 (gram path, per chunk): h1c = relu(BN1(aggc @ W1 + b1)) ----
__global__ __launch_bounds__(256, 2) void k_mlp1(const unsigned short* __restrict__ aggc,
                                                 const unsigned short* __restrict__ w1t,
                                                 const void* __restrict__ b1,
                                                 const void* __restrict__ g1,
                                                 const void* __restrict__ bb1,
                                                 const float* __restrict__ sum1,
                                                 const float* __restrict__ sumsq1,
                                                 unsigned short* __restrict__ h1c,
                                                 const int* __restrict__ flags) {
    __shared__ unsigned short bufA[128 * 128];   // 32 KB: X tile, then output tile
    __shared__ unsigned short bufW[128 * 128];   // 32 KB: W1 tile
    int isf = flags[0];
    int t = threadIdx.x;
    int m0 = (blockIdx.x >> 2) * 128;            // chunk-relative row
    int nb = blockIdx.x & 3;
    int r = t >> 1, half = t & 1;
    int wid = t >> 6, lane = t & 63;
    int wm = wid & 1, wn = wid >> 1;
    int quad = lane >> 4, l16 = lane & 15;
#pragma unroll
    for (int i = 0; i < 8; i++) {
        int chunk = half * 8 + i;
        int sw = ((chunk ^ (r & 15)) * 8);
        *(uint4*)(bufA + r * 128 + sw) = *(const uint4*)(aggc + (size_t)(m0 + r) * 128 + chunk * 8);
        *(uint4*)(bufW + r * 128 + sw) = *(const uint4*)(w1t + (size_t)(nb * 128 + r) * 128 + chunk * 8);
    }
    __syncthreads();
    f32x4 acc[4][4] = {};
#pragma unroll
    for (int ks = 0; ks < 4; ks++) {
        short8 af[4], bw[4];
#pragma unroll
        for (int mt = 0; mt < 4; mt++)
            af[mt] = *(const short8*)(bufA + (wm * 64 + mt * 16 + l16) * 128 + (((ks * 4 + quad) ^ l16) * 8));
#pragma unroll
        for (int nt = 0; nt < 4; nt++)
            bw[nt] = *(const short8*)(bufW + (wn * 64 + nt * 16 + l16) * 128 + (((ks * 4 + quad) ^ l16) * 8));
#pragma unroll
        for (int mt = 0; mt < 4; mt++)
#pragma unroll
            for (int nt = 0; nt < 4; nt++)
                acc[mt][nt] = __builtin_amdgcn_mfma_f32_16x16x32_bf16(af[mt], bw[nt], acc[mt][nt], 0, 0, 0);
    }
    __syncthreads();   // all LDS reads done; bufA reused for output
#pragma unroll
    for (int nt = 0; nt < 4; nt++) {
        int nl = wn * 64 + nt * 16 + l16;
        int n1 = nb * 128 + nl;
        float mz = sum1[n1] * (1.f / N_NODES);
        float vz = sumsq1[n1] * (1.f / N_NODES) - mz * mz;
        float inv = rsqrtf(fmaxf(vz, 0.f) + 1e-5f);
        float A = loadP(g1, n1, isf) * inv;
        float C = loadP(bb1, n1, isf) - mz * A + loadP(b1, n1, isf) * A;
        int ccw = nl >> 3, cl = nl & 7;
#pragma unroll
        for (int mt = 0; mt < 4; mt++)
#pragma unroll
            for (int rg = 0; rg < 4; rg++) {
                int R = wm * 64 + mt * 16 + quad * 4 + rg;
                bufA[R * 128 + ((ccw ^ (R & 15)) * 8) + cl] = f2bf(fmaxf(acc[mt][nt][rg] * A + C, 0.f));
            }
    }
    __syncthreads();
#pragma unroll
    for (int i = 0; i < 8; i++) {
        int idx = t + i * 256;                   // 2048 uint4 = full 32 KB tile
        int rr = idx >> 4, chunk = idx & 15;
        *(uint4*)(h1c + (size_t)(m0 + rr) * D_HID + nb * 128 + chunk * 8) =
            *(const uint4*)(bufA + rr * 128 + ((chunk ^ (rr & 15)) * 8));
    }
}

// ---- MLP stage 1 (big-ws path): h1 = agg @ W1 + b1 RAW, BN1 stats fused ----
__global__ __launch_bounds__(256, 2) void k_mlp1r(const unsigned short* __restrict__ aggb,
                                                  const unsigned short* __restrict__ w1t,
                                                  const void* __restrict__ b1,
                                                  unsigned short* __restrict__ h1,
                                                  float* __restrict__ sum1,
                                                  float* __restrict__ sumsq1,
                                                  const int* __restrict__ flags) {
    __shared__ unsigned short bufA[128 * 128];
    __shared__ unsigned short bufW[128 * 128];
    __shared__ float sred[256];
    int isf = flags[0];
    int t = threadIdx.x;
    int m0 = (blockIdx.x >> 2) * 128;
    int nb = blockIdx.x & 3;
    int r = t >> 1, half = t & 1;
    int wid = t >> 6, lane = t & 63;
    int wm = wid & 1, wn = wid >> 1;
    int quad = lane >> 4, l16 = lane & 15;
    sred[t] = 0.f;
#pragma unroll
    for (int i = 0; i < 8; i++) {
        int chunk = half * 8 + i;
        int sw = ((chunk ^ (r & 15)) * 8);
        *(uint4*)(bufA + r * 128 + sw) = *(const uint4*)(aggb + (size_t)(m0 + r) * 128 + chunk * 8);
        *(uint4*)(bufW + r * 128 + sw) = *(const uint4*)(w1t + (size_t)(nb * 128 + r) * 128 + chunk * 8);
    }
    __syncthreads();
    f32x4 acc[4][4] = {};
#pragma unroll
    for (int ks = 0; ks < 4; ks++) {
        short8 af[4], bw[4];
#pragma unroll
        for (int mt = 0; mt < 4; mt++)
            af[mt] = *(const short8*)(bufA + (wm * 64 + mt * 16 + l16) * 128 + (((ks * 4 + quad) ^ l16) * 8));
#pragma unroll
        for (int nt = 0; nt < 4; nt++)
            bw[nt] = *(const short8*)(bufW + (wn * 64 + nt * 16 + l16) * 128 + (((ks * 4 + quad) ^ l16) * 8));
#pragma unroll
        for (int mt = 0; mt < 4; mt++)
#pragma unroll
            for (int nt = 0; nt < 4; nt++)
                acc[mt][nt] = __builtin_amdgcn_mfma_f32_16x16x32_bf16(af[mt], bw[nt], acc[mt][nt], 0, 0, 0);
    }
    __syncthreads();
    // epilogue: z = acc + b1 (raw), stats, bf16 -> bufA swizzled
#pragma unroll
    for (int nt = 0; nt < 4; nt++) {
        int nl = wn * 64 + nt * 16 + l16;
        int n1 = nb * 128 + nl;
        float bias = loadP(b1, n1, isf);
        int ccw = nl >> 3, cl = nl & 7;
        float s = 0.f, ss = 0.f;
#pragma unroll
        for (int mt = 0; mt < 4; mt++)
#pragma unroll
            for (int rg = 0; rg < 4; rg++) {
                int R = wm * 64 + mt * 16 + quad * 4 + rg;
                float z = acc[mt][nt][rg] + bias;
                bufA[R * 128 + ((ccw ^ (R & 15)) * 8) + cl] = f2bf(z);
                if (m0 + R < N_NODES) { s += z; ss += z * z; }
            }
        s += __shfl_xor(s, 16, 64); ss += __shfl_xor(ss, 16, 64);
        s += __shfl_xor(s, 32, 64); ss += __shfl_xor(ss, 32, 64);
        if (quad == 0) { atomicAdd(&sred[nl], s); atomicAdd(&sred[128 + nl], ss); }
    }
    __syncthreads();
#pragma unroll
    for (int i = 0; i < 8; i++) {
        int idx = t + i * 256;
        int rr = idx >> 4, chunk = idx & 15;
        *(uint4*)(h1 + (size_t)(m0 + rr) * D_HID + nb * 128 + chunk * 8) =
            *(const uint4*)(bufA + rr * 128 + ((chunk ^ (rr & 15)) * 8));
    }
    if (t < 128)      atomicAdd(&sum1[nb * 128 + t], sred[t]);
    else              atomicAdd(&sumsq1[nb * 128 + (t - 128)], sred[t]);
}

// ---- MLP stage 2 (gram path, per chunk): h2c = h1c @ W2 + b2, BN2 stats fused ----
__global__ __launch_bounds__(256, 3) void k_mlp2(const unsigned short* __restrict__ h1c,
                                                 const unsigned short* __restrict__ w2t,
                                                 const void* __restrict__ b2,
                                                 unsigned short* __restrict__ h2c,
                                                 float* __restrict__ sum2,
                                                 float* __restrict__ sumsq2,
                                                 const int* __restrict__ flags,
                                                 int roff) {
    __shared__ unsigned short bufA[64 * 128];
    __shared__ unsigned short bufW[128 * 128];
    __shared__ float sred[256];
    int isf = flags[0];
    int t = threadIdx.x;
    int m0 = blockIdx.x * 64;
    int rw = t >> 1, halfw = t & 1;
    int wid = t >> 6, lane = t & 63;
    int wm = wid & 1, wn = wid >> 1;
    int quad = lane >> 4, l16 = lane & 15;
    sred[t] = 0.f;
    f32x4 acc[2][4] = {};
    for (int kb = 0; kb < 4; kb++) {
        __syncthreads();
#pragma unroll
        for (int i = 0; i < 4; i++) {
            int idx = t + i * 256;
            int rr = idx >> 4, chunk = idx & 15;
            *(uint4*)(bufA + rr * 128 + ((chunk ^ (rr & 15)) * 8)) =
                *(const uint4*)(h1c + (size_t)(m0 + rr) * D_HID + kb * 128 + chunk * 8);
        }
#pragma unroll
        for (int i = 0; i < 8; i++) {
            int chunk = halfw * 8 + i;
            *(uint4*)(bufW + rw * 128 + ((chunk ^ (rw & 15)) * 8)) =
                *(const uint4*)(w2t + (size_t)rw * D_HID + kb * 128 + chunk * 8);
        }
        __syncthreads();
#pragma unroll
        for (int ks = 0; ks < 4; ks++) {
            short8 af[2], bw[4];
#pragma unroll
            for (int mt = 0; mt < 2; mt++)
                af[mt] = *(const short8*)(bufA + (wm * 32 + mt * 16 + l16) * 128 + (((ks * 4 + quad) ^ l16) * 8));
#pragma unroll
            for (int nt = 0; nt < 4; nt++)
                bw[nt] = *(const short8*)(bufW + (wn * 64 + nt * 16 + l16) * 128 + (((ks * 4 + quad) ^ l16) * 8));
#pragma unroll
            for (int mt = 0; mt < 2; mt++)
#pragma unroll
                for (int nt = 0; nt < 4; nt++)
                    acc[mt][nt] = __builtin_amdgcn_mfma_f32_16x16x32_bf16(af[mt], bw[nt], acc[mt][nt], 0, 0, 0);
        }
    }
    __syncthreads();
#pragma unroll
    for (int nt = 0; nt < 4; nt++) {
        int n = wn * 64 + nt * 16 + l16;
        float bias = loadP(b2, n, isf);
        float s = 0.f, ss = 0.f;
#pragma unroll
        for (int mt = 0; mt < 2; mt++) {
            int Rl = wm * 32 + mt * 16 + quad * 4;
#pragma unroll
            for (int rg = 0; rg < 4; rg++) {
                float z = acc[mt][nt][rg] + bias;
                bufW[(Rl + rg) * 128 + n] = f2bf(z);
                if (roff + m0 + Rl + rg < N_NODES) { s += z; ss += z * z; }
            }
        }
        s += __shfl_xor(s, 16, 64); ss += __shfl_xor(ss, 16, 64);
        s += __shfl_xor(s, 32, 64); ss += __shfl_xor(ss, 32, 64);
        if (quad == 0) { atomicAdd(&sred[n], s); atomicAdd(&sred[128 + n], ss); }
    }
    __syncthreads();
#pragma unroll
    for (int i = 0; i < 4; i++) {
        int idx = t + i * 256;
        int rr = idx >> 4, seg = idx & 15;
        *(uint4*)(h2c + (size_t)(m0 + rr) * D_IN + seg * 8) = *(const uint4*)(bufW + rr * 128 + seg * 8);
    }
    {
        int n = t & 127;
        if (t < 128) atomicAdd(&sum2[n], sred[n]);
        else         atomicAdd(&sumsq2[n], sred[128 + n]);
    }
}

// ---- MLP stage 2 (big-ws path): BM=128, 8 waves; BN1+ReLU on staging with
// vectorized coeff reads (chunk = t&15 is i-invariant) ----
__global__ __launch_bounds__(512, 4) void k_mlp2b(const unsigned short* __restrict__ h1,
                                                  const unsigned short* __restrict__ w2t,
                                                  const void* __restrict__ b2,
                                                  const void* __restrict__ g1,
                                                  const void* __restrict__ bb1,
                                                  const float* __restrict__ sum1,
                                                  const float* __restrict__ sumsq1,
                                                  unsigned short* __restrict__ h2,
                                                  float* __restrict__ sum2,
                                                  float* __restrict__ sumsq2,
                                                  const int* __restrict__ flags) {
    __shared__ unsigned short bufA[128 * 128];   // 32 KB: relu(BN1(h1)) K-slice
    __shared__ unsigned short bufW[128 * 128];   // 32 KB: w2t K-slice / h2 staging
    __shared__ float sred[256];
    __shared__ __align__(16) float bnA[512];
    __shared__ __align__(16) float bnC[512];
    int isf = flags[0];
    int t = threadIdx.x;
    int m0 = blockIdx.x * 128;
    int wid = t >> 6, lane = t & 63;
    int wm = wid & 3, wn = wid >> 2;             // 4 row-groups x 2 col-groups
    int quad = lane >> 4, l16 = lane & 15;
    int chunkT = t & 15;                         // i-invariant column chunk
    if (t < 256) sred[t] = 0.f;
    if (t < 512) {
        float mz = sum1[t] * (1.f / N_NODES);
        float vz = sumsq1[t] * (1.f / N_NODES) - mz * mz;
        float inv = rsqrtf(fmaxf(vz, 0.f) + 1e-5f);
        float A = loadP(g1, t, isf) * inv;
        bnA[t] = A;
        bnC[t] = loadP(bb1, t, isf) - mz * A;    // b1 already inside raw h1
    }
    f32x4 acc[2][4] = {};
    for (int kb = 0; kb < 4; kb++) {
        __syncthreads();   // first iter covers bnA/bnC/sred init; later: prev LDS reads done
        f32x4 A0 = *(const f32x4*)(bnA + kb * 128 + chunkT * 8);
        f32x4 A1 = *(const f32x4*)(bnA + kb * 128 + chunkT * 8 + 4);
        f32x4 C0 = *(const f32x4*)(bnC + kb * 128 + chunkT * 8);
        f32x4 C1 = *(const f32x4*)(bnC + kb * 128 + chunkT * 8 + 4);
        // stage A: relu(BN1(h1)) rows m0..m0+127, cols kb*128..+128
#pragma unroll
        for (int i = 0; i < 4; i++) {
            int idx = t + i * 512;
            int rr = idx >> 4;
            uint4 v = *(const uint4*)(h1 + (size_t)(m0 + rr) * D_HID + kb * 128 + chunkT * 8);
            const unsigned short* pv = (const unsigned short*)&v;
            unsigned short o[8];
            o[0] = f2bf(fmaxf(bf2f(pv[0]) * A0[0] + C0[0], 0.f));
            o[1] = f2bf(fmaxf(bf2f(pv[1]) * A0[1] + C0[1], 0.f));
            o[2] = f2bf(fmaxf(bf2f(pv[2]) * A0[2] + C0[2], 0.f));
            o[3] = f2bf(fmaxf(bf2f(pv[3]) * A0[3] + C0[3], 0.f));
            o[4] = f2bf(fmaxf(bf2f(pv[4]) * A1[0] + C1[0], 0.f));
            o[5] = f2bf(fmaxf(bf2f(pv[5]) * A1[1] + C1[1], 0.f));
            o[6] = f2bf(fmaxf(bf2f(pv[6]) * A1[2] + C1[2], 0.f));
            o[7] = f2bf(fmaxf(bf2f(pv[7]) * A1[3] + C1[3], 0.f));
            *(uint4*)(bufA + rr * 128 + ((chunkT ^ (rr & 15)) * 8)) = *(const uint4*)o;
        }
        // stage W: w2t rows 0..127 (output cols), cols kb*128..+128
#pragma unroll
        for (int i = 0; i < 4; i++) {
            int idx = t + i * 512;
            int rr = idx >> 4;
            *(uint4*)(bufW + rr * 128 + ((chunkT ^ (rr & 15)) * 8)) =
                *(const uint4*)(w2t + (size_t)rr * D_HID + kb * 128 + chunkT * 8);
        }
        __syncthreads();
#pragma unroll
        for (int ks = 0; ks < 4; ks++) {
            short8 af[2], bw[4];
#pragma unroll
            for (int mt = 0; mt < 2; mt++)
                af[mt] = *(const short8*)(bufA + (wm * 32 + mt * 16 + l16) * 128 + (((ks * 4 + quad) ^ l16) * 8));
#pragma unroll
            for (int nt = 0; nt < 4; nt++)
                bw[nt] = *(const short8*)(bufW + (wn * 64 + nt * 16 + l16) * 128 + (((ks * 4 + quad) ^ l16) * 8));
#pragma unroll
            for (int mt = 0; mt < 2; mt++)
#pragma unroll
                for (int nt = 0; nt < 4; nt++)
                    acc[mt][nt] = __builtin_amdgcn_mfma_f32_16x16x32_bf16(af[mt], bw[nt], acc[mt][nt], 0, 0, 0);
        }
    }
    __syncthreads();       // last LDS reads done; bufW reused for h2 staging
    // epilogue: +b2, BN2 stats (LDS pre-reduce), h2 tile staged row-major
#pragma unroll
    for (int nt = 0; nt < 4; nt++) {
        int n = wn * 64 + nt * 16 + l16;
        float bias = loadP(b2, n, isf);
        float s = 0.f, ss = 0.f;
#pragma unroll
        for (int mt = 0; mt < 2; mt++) {
            int Rl = wm * 32 + mt * 16 + quad * 4;
#pragma unroll
            for (int rg = 0; rg < 4; rg++) {
                float z = acc[mt][nt][rg] + bias;
                bufW[(Rl + rg) * 128 + n] = f2bf(z);
                if (m0 + Rl + rg < N_NODES) { s += z; ss += z * z; }
            }
        }
        s += __shfl_xor(s, 16, 64); ss += __shfl_xor(ss, 16, 64);
        s += __shfl_xor(s, 32, 64); ss += __shfl_xor(ss, 32, 64);
        if (quad == 0) { atomicAdd(&sred[n], s); atomicAdd(&sred[128 + n], ss); }
    }
    __syncthreads();
#pragma unroll
    for (int i = 0; i < 4; i++) {
        int idx = t + i * 512;                   // 2048 uint4 = 32 KB (128x128 tile)
        int rr = idx >> 4, seg = idx & 15;
        *(uint4*)(h2 + (size_t)(m0 + rr) * D_IN + seg * 8) = *(const uint4*)(bufW + rr * 128 + seg * 8);
    }
    if (t < 256) {
        int n = t & 127;
        if (t < 128) atomicAdd(&sum2[n], sred[n]);
        else         atomicAdd(&sumsq2[n], sred[128 + n]);
    }
}

// ---- BN2 + ReLU + residual + LayerNorm -> out (h2 bf16 input) ----
__global__ __launch_bounds__(256) void k_final(const unsigned short* __restrict__ h2,
                                               const void* __restrict__ x,
                                               const float* __restrict__ sum2,
                                               const float* __restrict__ sumsq2,
                                               const void* __restrict__ g2,
                                               const void* __restrict__ bb2,
                                               const void* __restrict__ lng,
                                               const void* __restrict__ lnb,
                                               void* __restrict__ out,
                                               const int* __restrict__ flags) {
    int isf = flags[0];
    __shared__ float a2s[D_IN], c2s[D_IN];
    int t = threadIdx.x;
    if (t < D_IN) {
        float m = sum2[t] * (1.f / N_NODES);
        float v = sumsq2[t] * (1.f / N_NODES) - m * m;
        float inv = rsqrtf(fmaxf(v, 0.f) + 1e-5f);
        float a = loadP(g2, t, isf) * inv;
        a2s[t] = a;
        c2s[t] = loadP(bb2, t, isf) - m * a;
    }
    __syncthreads();
    int w = t >> 6, lane = t & 63;
    int row = blockIdx.x * 4 + w;
    if (row >= N_NODES) return;
    size_t base = (size_t)row * D_IN;
    int c0 = lane * 2, c1 = lane * 2 + 1;
    unsigned int hu = ((const unsigned int*)h2)[base / 2 + lane];
    float x0, x1;
    if (isf) {
        float2 xv = *((const float2*)x + base / 2 + lane);
        x0 = xv.x; x1 = xv.y;
    } else {
        unsigned int xu = ((const unsigned int*)x)[base / 2 + lane];
        x0 = bf2f(xu & 0xffff); x1 = bf2f(xu >> 16);
    }
    float o0 = fmaxf(a2s[c0] * bf2f(hu & 0xffff) + c2s[c0], 0.f) + x0;
    float o1 = fmaxf(a2s[c1] * bf2f(hu >> 16) + c2s[c1], 0.f) + x1;
    float s = o0 + o1, ss = o0 * o0 + o1 * o1;
#pragma unroll
    for (int m = 1; m < 64; m <<= 1) {
        s += __shfl_xor(s, m, 64);
        ss += __shfl_xor(ss, m, 64);
    }
    float mean = s * (1.f / D_IN);
    float var = ss * (1.f / D_IN) - mean * mean;
    float inv = rsqrtf(fmaxf(var, 0.f) + 1e-5f);
    float r0 = (o0 - mean) * inv * loadP(lng, c0, isf) + loadP(lnb, c0, isf);
    float r1 = (o1 - mean) * inv * loadP(lng, c1, isf) + loadP(lnb, c1, isf);
    if (isf) {
        *((float2*)out + base / 2 + lane) = make_float2(r0, r1);
    } else {
        ((unsigned int*)out)[base / 2 + lane] = (unsigned int)f2bf(r0) | ((unsigned int)f2bf(r1) << 16);
    }
}

extern "C" void kernel_launch(void* const* d_in, const int* in_sizes, int n_in,
                              void* d_out, int out_size, void* d_ws, size_t ws_size,
                              hipStream_t stream) {
    const void* x    = d_in[0];
    const int*  ei   = (const int*)d_in[1];
    const void* W1   = d_in[2];
    const void* b1   = d_in[3];
    const void* bn1g = d_in[4];
    const void* bn1b = d_in[5];
    const void* W2   = d_in[6];
    const void* b2   = d_in[7];
    const void* bn2g = d_in[8];
    const void* bn2b = d_in[9];
    const void* lng  = d_in[10];
    const void* lnb  = d_in[11];

    // workspace: phase A peaks at 33.53 MB; big-ws path (h1 full) needs 64.8 MB.
    char* ws = (char*)d_ws;
    float* stats   = (float*)ws;                      // 1408 f32
    float* sum1    = stats;
    float* sumsq1  = stats + 512;
    float* sum2    = stats + 1024;
    float* sumsq2  = stats + 1152;
    float* colsum  = stats + 1280;
    int*   flags   = (int*)(ws + 5632);
    int*   partials= (int*)(ws + 5696);
    int*   rowptr  = (int*)(ws + 8192);               // 50001 ints
    int*   cursor  = (int*)(ws + 208256);             // 50000 ints
    unsigned short* w1t = (unsigned short*)(ws + 408320);   // [512][128] bf16
    unsigned short* w2t = (unsigned short*)(ws + 539392);   // [128][512] bf16
    float* G       = (float*)(ws + 670464);           // 128x128 f32 -> ends 736000
    unsigned short* agg = (unsigned short*)(ws + 736000);   // NPAD*128 bf16 -> ends 13548288; reused as h2
    unsigned short* h2  = agg;
    int*   bucket  = (int*)(ws + 13548288);           // 800000 ints (dead after gather)
    float* Gpart   = (float*)(ws + 16748288);         // 256 x 16384 f32 (16 MB) -> ends 33525504
    unsigned short* h1r = (unsigned short*)(ws + 13548288); // overlays bucket+Gpart

    k_init<<<202, 256, 0, stream>>>(x, ei, stats, cursor, flags);
    k_prep<<<512 + 8 * FILL_SUB, 256, 0, stream>>>(W1, W2, w1t, w2t, ei, cursor, flags);
    k_scan_block<<<SCAN_NB, 256, 0, stream>>>(cursor, rowptr, partials);
    k_scan_add<<<SCAN_NB, 256, 0, stream>>>(rowptr, cursor, partials);
    k_fill<<<8 * FILL_SUB, 256, 0, stream>>>(ei, cursor, bucket, flags);
    k_gather<<<NPAD / 4, 256, 0, stream>>>(rowptr, bucket, x, agg, flags);

    if ((long long)ws_size >= H1_FULL_NEED) {
        // big-ws path: raw h1 + fused BN1 stats; no gram/gred/bn1; single pass
        k_mlp1r<<<NTILES * 4, 256, 0, stream>>>(agg, w1t, b1, h1r, sum1, sumsq1, flags);
        k_mlp2b<<<NTILES, 512, 0, stream>>>(h1r, w2t, b2, bn1g, bn1b, sum1, sumsq1,
                                            h2, sum2, sumsq2, flags);
    } else {
        k_gram<<<G_BLOCKS, 256, 0, stream>>>(agg, Gpart, colsum);
        k_gred<<<64, 256, 0, stream>>>(Gpart, G);
        k_bn1<<<128, 256, 0, stream>>>(G, colsum, w1t, b1, sum1, sumsq1, flags);
        long long avail = (long long)ws_size - 13548288LL;
        int max_tiles = (avail > 0) ? (int)(avail / 131072LL) : 1;
        if (max_tiles < 1)  max_tiles = 1;
        if (max_tiles > NTILES) max_tiles = NTILES;
        int nch = (NTILES + max_tiles - 1) / max_tiles;
        int per = (NTILES + nch - 1) / nch;
        for (int done = 0; done < NTILES; done += per) {
            int nt = NTILES - done;
            if (nt > per) nt = per;
            const unsigned short* aggc = agg + (size_t)done * 128 * 128;
            unsigned short* h2c = h2 + (size_t)done * 128 * 128;
            k_mlp1<<<nt * 4, 256, 0, stream>>>(aggc, w1t, b1, bn1g, bn1b, sum1, sumsq1, h1r, flags);
            k_mlp2<<<nt * 2, 256, 0, stream>>>(h1r, w2t, b2, h2c, sum2, sumsq2, flags, done * 128);
        }
    }

    k_final<<<(N_NODES + 3) / 4, 256, 0, stream>>>(h2, x, sum2, sumsq2, bn2g, bn2b, lng, lnb, d_out, flags);
}

// Round 13
// 319.923 us; speedup vs baseline: 1.3429x; 1.0143x over previous
//
#include <hip/hip_runtime.h>
#include <stdint.h>

#define N_NODES 50000
#define N_EDGES 800000
#define D_IN    128
#define D_HID   512
#define NPAD    50048   // 391 * 128
#define NTILES  391     // NPAD / 128
#define SCAN_NB 196     // ceil(50000/256)
#define G_TILES 782     // NPAD / 64
#define G_BLOCKS 256
#define H1_SEP_NEED   64797440LL   // h1r at 13548288 (bucket dead before mlp1r)
#define H1_FUSED_NEED 67997440LL   // h1r at 16748288 (coexists with live bucket)
#define FILL_CH 2048              // edges per block chunk (256 thr x 8)
#define FILL_SUB ((N_EDGES + FILL_CH - 1) / FILL_CH)   // 391

typedef __attribute__((ext_vector_type(8))) short short8;
typedef __attribute__((ext_vector_type(4))) float f32x4;

__device__ __forceinline__ float bf2f(unsigned short u) {
    union { unsigned int i; float f; } v; v.i = ((unsigned int)u) << 16; return v.f;
}
__device__ __forceinline__ unsigned short f2bf(float f) {
    union { float f; unsigned int i; } v; v.f = f;
    unsigned int r = v.i + 0x7fffu + ((v.i >> 16) & 1u);
    return (unsigned short)(r >> 16);
}
__device__ __forceinline__ float loadP(const void* p, long i, int isf) {
    return isf ? ((const float*)p)[i] : bf2f(((const unsigned short*)p)[i]);
}

// ---- fused: zero all stats(1408)+counts (blocks 0..200) + detect flags (block 201) ----
__global__ void k_init(const void* __restrict__ x, const int* __restrict__ ei,
                       float* __restrict__ stats, int* __restrict__ counts,
                       int* __restrict__ flags) {
    int t = threadIdx.x;
    if (blockIdx.x < 201) {
        int i = blockIdx.x * 256 + t;
        if (i < 1408) stats[i] = 0.f;                     // sum1|sumsq1|sum2|sumsq2|colsum
        else if (i < 1408 + N_NODES) counts[i - 1408] = 0;
    } else {
        __shared__ int sh[2];
        if (t == 0) { sh[0] = 0; sh[1] = 1; }
        __syncthreads();
        const unsigned short* xu = (const unsigned short*)x;
        for (int i = t; i < 8192; i += 256)
            if (((xu[i] >> 7) & 0xFF) == 0xFF) sh[0] = 1;   // benign race
        for (int k = t; k < 64; k += 256)
            if (ei[2 * k + 1] != 0) sh[1] = 0;
        __syncthreads();
        if (t == 0) { flags[0] = sh[0]; flags[1] = sh[1]; }
    }
}

// ---- merged: weight transposes (blocks 0..511) + in-degree count (blocks 512+) ----
__global__ __launch_bounds__(256) void k_prep(const void* __restrict__ W1, const void* __restrict__ W2,
                                              unsigned short* __restrict__ w1t, unsigned short* __restrict__ w2t,
                                              const int* __restrict__ ei, int* __restrict__ counts,
                                              const int* __restrict__ flags) {
    int isf = flags[0];
    if (blockIdx.x < 512) {
        int idx = blockIdx.x * 256 + threadIdx.x;     // 131072 threads
        if (idx < D_IN * D_HID) {
            int n = idx >> 7, k = idx & 127;          // w1t[n][k] = W1[k][n]
            int src = k * D_HID + n;
            w1t[idx] = isf ? f2bf(((const float*)W1)[src])
                           : ((const unsigned short*)W1)[src];
        } else {
            int j = idx - D_IN * D_HID;
            int n = j >> 9, k = j & 511;              // w2t[n][k] = W2[k][n]
            int src = k * D_IN + n;
            w2t[j] = isf ? f2bf(((const float*)W2)[src])
                         : ((const unsigned short*)W2)[src];
        }
    } else {
        int i64 = flags[1];
        int bid = blockIdx.x - 512;
        int gid = bid & 7;
        int sub = bid >> 3;
        int lo = gid * (N_NODES / 8), hi = lo + (N_NODES / 8);
        int base = sub * FILL_CH + threadIdx.x;
#pragma unroll
        for (int i = 0; i < 8; i++) {
            int e = base + i * 256;
            if (e < N_EDGES) {
                int d = i64 ? ei[2 * N_EDGES + 2 * e] : ei[N_EDGES + e];
                d = min(max(d, 0), N_NODES - 1);
                if (d >= lo && d < hi) atomicAdd(&counts[d], 1);
            }
        }
    }
}

// ---- CSR step 2a: per-block exclusive scan; block sums -> partials (raw) ----
__global__ __launch_bounds__(256) void k_scan_block(const int* __restrict__ counts,
                                                    int* __restrict__ rowptr,
                                                    int* __restrict__ partials) {
    __shared__ int a[256], b[256];
    int t = threadIdx.x;
    int idx = blockIdx.x * 256 + t;
    int c = (idx < N_NODES) ? counts[idx] : 0;
    a[t] = c;
    __syncthreads();
    int* src = a; int* dst = b;
    for (int off = 1; off < 256; off <<= 1) {
        dst[t] = src[t] + ((t >= off) ? src[t - off] : 0);
        __syncthreads();
        int* tmp = src; src = dst; dst = tmp;
    }
    if (idx < N_NODES) rowptr[idx] = src[t] - c;
    if (t == 255) partials[blockIdx.x] = src[255];
}

// ---- CSR step 2b+2c merged: per-block prefix reduce + add; mirror to cursor ----
__global__ __launch_bounds__(256) void k_scan_add(int* __restrict__ rowptr, int* __restrict__ cursor,
                                                  const int* __restrict__ partials) {
    __shared__ int red[256];
    int t = threadIdx.x, bid = blockIdx.x;
    red[t] = (t < SCAN_NB && t < bid) ? partials[t] : 0;
    __syncthreads();
#pragma unroll
    for (int off = 128; off > 0; off >>= 1) {
        if (t < off) red[t] += red[t + off];
        __syncthreads();
    }
    int prefix = red[0];
    int idx = bid * 256 + t;
    if (idx < N_NODES) {
        int v = rowptr[idx] + prefix;
        rowptr[idx] = v;
        cursor[idx] = v;
    } else if (idx == N_NODES) {
        rowptr[N_NODES] = N_EDGES;
    }
}

// ---- CSR step 3: fill buckets, dst-range partitioned to XCDs (verified r9) ----
__global__ __launch_bounds__(256) void k_fill(const int* __restrict__ ei, int* __restrict__ cursor,
                                              int* __restrict__ bucket, const int* __restrict__ flags) {
    int i64 = flags[1];
    int gid = blockIdx.x & 7;
    int sub = blockIdx.x >> 3;
    int lo = gid * (N_NODES / 8), hi = lo + (N_NODES / 8);   // 6250 each, exact
    int base = sub * FILL_CH + threadIdx.x;
#pragma unroll
    for (int i = 0; i < 8; i++) {
        int e = base + i * 256;
        if (e < N_EDGES) {
            int d = i64 ? ei[2 * N_EDGES + 2 * e] : ei[N_EDGES + e];
            d = min(max(d, 0), N_NODES - 1);
            if (d >= lo && d < hi) {
                int s = i64 ? ei[2 * e] : ei[e];
                s = min(max(s, 0), N_NODES - 1);
                int pos = atomicAdd(&cursor[d], 1);
                bucket[pos] = s;
            }
        }
    }
}

// ---- gather-sum, 8-way ILP (gram/sep paths; fused path has its own gather) ----
__global__ __launch_bounds__(256) void k_gather(const int* __restrict__ rowptr,
                                                const int* __restrict__ bucket,
                                                const void* __restrict__ x,
                                                unsigned short* __restrict__ agg,
                                                const int* __restrict__ flags) {
    int isf = flags[0];
    int w = threadIdx.x >> 6, lane = threadIdx.x & 63;
    int row = blockIdx.x * 4 + w;          // grid = NPAD/4, exact
    float a0 = 0.f, a1 = 0.f;
    if (row < N_NODES) {
        int beg = rowptr[row], end = rowptr[row + 1];
        if (isf) {
            const float* xf = (const float*)x;
            float2 v = *(const float2*)(xf + (size_t)row * D_IN + lane * 2);
            a0 = v.x; a1 = v.y;
            int j = beg;
            for (; j + 8 <= end; j += 8) {
                float2 n0 = *(const float2*)(xf + (size_t)bucket[j] * D_IN + lane * 2);
                float2 n1 = *(const float2*)(xf + (size_t)bucket[j + 1] * D_IN + lane * 2);
                float2 n2 = *(const float2*)(xf + (size_t)bucket[j + 2] * D_IN + lane * 2);
                float2 n3 = *(const float2*)(xf + (size_t)bucket[j + 3] * D_IN + lane * 2);
                float2 n4 = *(const float2*)(xf + (size_t)bucket[j + 4] * D_IN + lane * 2);
                float2 n5 = *(const float2*)(xf + (size_t)bucket[j + 5] * D_IN + lane * 2);
                float2 n6 = *(const float2*)(xf + (size_t)bucket[j + 6] * D_IN + lane * 2);
                float2 n7 = *(const float2*)(xf + (size_t)bucket[j + 7] * D_IN + lane * 2);
                a0 += ((n0.x + n1.x) + (n2.x + n3.x)) + ((n4.x + n5.x) + (n6.x + n7.x));
                a1 += ((n0.y + n1.y) + (n2.y + n3.y)) + ((n4.y + n5.y) + (n6.y + n7.y));
            }
            for (; j + 4 <= end; j += 4) {
                float2 n0 = *(const float2*)(xf + (size_t)bucket[j] * D_IN + lane * 2);
                float2 n1 = *(const float2*)(xf + (size_t)bucket[j + 1] * D_IN + lane * 2);
                float2 n2 = *(const float2*)(xf + (size_t)bucket[j + 2] * D_IN + lane * 2);
                float2 n3 = *(const float2*)(xf + (size_t)bucket[j + 3] * D_IN + lane * 2);
                a0 += (n0.x + n1.x) + (n2.x + n3.x);
                a1 += (n0.y + n1.y) + (n2.y + n3.y);
            }
            for (; j < end; j++) {
                float2 n = *(const float2*)(xf + (size_t)bucket[j] * D_IN + lane * 2);
                a0 += n.x; a1 += n.y;
            }
        } else {
            const unsigned int* xu = (const unsigned int*)x;
            unsigned int u = xu[(size_t)row * 64 + lane];
            a0 = bf2f(u & 0xffff); a1 = bf2f(u >> 16);
            int j = beg;
            for (; j + 8 <= end; j += 8) {
                unsigned int u0 = xu[(size_t)bucket[j] * 64 + lane];
                unsigned int u1 = xu[(size_t)bucket[j + 1] * 64 + lane];
                unsigned int u2 = xu[(size_t)bucket[j + 2] * 64 + lane];
                unsigned int u3 = xu[(size_t)bucket[j + 3] * 64 + lane];
                unsigned int u4 = xu[(size_t)bucket[j + 4] * 64 + lane];
                unsigned int u5 = xu[(size_t)bucket[j + 5] * 64 + lane];
                unsigned int u6 = xu[(size_t)bucket[j + 6] * 64 + lane];
                unsigned int u7 = xu[(size_t)bucket[j + 7] * 64 + lane];
                a0 += ((bf2f(u0 & 0xffff) + bf2f(u1 & 0xffff)) + (bf2f(u2 & 0xffff) + bf2f(u3 & 0xffff)))
                    + ((bf2f(u4 & 0xffff) + bf2f(u5 & 0xffff)) + (bf2f(u6 & 0xffff) + bf2f(u7 & 0xffff)));
                a1 += ((bf2f(u0 >> 16) + bf2f(u1 >> 16)) + (bf2f(u2 >> 16) + bf2f(u3 >> 16)))
                    + ((bf2f(u4 >> 16) + bf2f(u5 >> 16)) + (bf2f(u6 >> 16) + bf2f(u7 >> 16)));
            }
            for (; j + 4 <= end; j += 4) {
                unsigned int u0 = xu[(size_t)bucket[j] * 64 + lane];
                unsigned int u1 = xu[(size_t)bucket[j + 1] * 64 + lane];
                unsigned int u2 = xu[(size_t)bucket[j + 2] * 64 + lane];
                unsigned int u3 = xu[(size_t)bucket[j + 3] * 64 + lane];
                a0 += (bf2f(u0 & 0xffff) + bf2f(u1 & 0xffff)) + (bf2f(u2 & 0xffff) + bf2f(u3 & 0xffff));
                a1 += (bf2f(u0 >> 16) + bf2f(u1 >> 16)) + (bf2f(u2 >> 16) + bf2f(u3 >> 16));
            }
            for (; j < end; j++) {
                unsigned int n = xu[(size_t)bucket[j] * 64 + lane];
                a0 += bf2f(n & 0xffff); a1 += bf2f(n >> 16);
            }
        }
    }
    unsigned int o = (unsigned int)f2bf(a0) | ((unsigned int)f2bf(a1) << 16);
    ((unsigned int*)agg)[(size_t)row * 64 + lane] = o;
}

// ---- FUSED gather + GEMM1 (big-ws path): gather 128 rows into LDS, then
// h1 = Xg @ W1 + b1 (raw) with BN1 stats. Overlaps gather latency with MFMA
// across co-resident blocks and skips the agg HBM round-trip. ----
__global__ __launch_bounds__(512, 4) void k_gmlp1(const int* __restrict__ rowptr,
                                                  const int* __restrict__ bucket,
                                                  const void* __restrict__ x,
                                                  const unsigned short* __restrict__ w1t,
                                                  const void* __restrict__ b1,
                                                  unsigned short* __restrict__ h1,
                                                  float* __restrict__ sum1,
                                                  float* __restrict__ sumsq1,
                                                  const int* __restrict__ flags) {
    __shared__ unsigned short bufA[128 * 128];   // 32 KB: gathered X tile (swizzled)
    __shared__ unsigned short bufW[128 * 128];   // 32 KB: W1 tile / h1 staging
    __shared__ float sred[256];
    int isf = flags[0];
    int t = threadIdx.x;
    int m0 = blockIdx.x * 128;
    int w8 = t >> 6, lane = t & 63;
    if (t < 256) sred[t] = 0.f;
    // ---- gather phase: wave w8 handles rows w8*16 .. w8*16+15 ----
    for (int rl = 0; rl < 16; rl++) {
        int r = w8 * 16 + rl;
        int row = m0 + r;
        float a0 = 0.f, a1 = 0.f;
        if (row < N_NODES) {
            int beg = rowptr[row], end = rowptr[row + 1];
            if (isf) {
                const float* xf = (const float*)x;
                float2 v = *(const float2*)(xf + (size_t)row * D_IN + lane * 2);
                a0 = v.x; a1 = v.y;
                int j = beg;
                for (; j + 8 <= end; j += 8) {
                    float2 n0 = *(const float2*)(xf + (size_t)bucket[j] * D_IN + lane * 2);
                    float2 n1 = *(const float2*)(xf + (size_t)bucket[j + 1] * D_IN + lane * 2);
                    float2 n2 = *(const float2*)(xf + (size_t)bucket[j + 2] * D_IN + lane * 2);
                    float2 n3 = *(const float2*)(xf + (size_t)bucket[j + 3] * D_IN + lane * 2);
                    float2 n4 = *(const float2*)(xf + (size_t)bucket[j + 4] * D_IN + lane * 2);
                    float2 n5 = *(const float2*)(xf + (size_t)bucket[j + 5] * D_IN + lane * 2);
                    float2 n6 = *(const float2*)(xf + (size_t)bucket[j + 6] * D_IN + lane * 2);
                    float2 n7 = *(const float2*)(xf + (size_t)bucket[j + 7] * D_IN + lane * 2);
                    a0 += ((n0.x + n1.x) + (n2.x + n3.x)) + ((n4.x + n5.x) + (n6.x + n7.x));
                    a1 += ((n0.y + n1.y) + (n2.y + n3.y)) + ((n4.y + n5.y) + (n6.y + n7.y));
                }
                for (; j + 4 <= end; j += 4) {
                    float2 n0 = *(const float2*)(xf + (size_t)bucket[j] * D_IN + lane * 2);
                    float2 n1 = *(const float2*)(xf + (size_t)bucket[j + 1] * D_IN + lane * 2);
                    float2 n2 = *(const float2*)(xf + (size_t)bucket[j + 2] * D_IN + lane * 2);
                    float2 n3 = *(const float2*)(xf + (size_t)bucket[j + 3] * D_IN + lane * 2);
                    a0 += (n0.x + n1.x) + (n2.x + n3.x);
                    a1 += (n0.y + n1.y) + (n2.y + n3.y);
                }
                for (; j < end; j++) {
                    float2 n = *(const float2*)(xf + (size_t)bucket[j] * D_IN + lane * 2);
                    a0 += n.x; a1 += n.y;
                }
            } else {
                const unsigned int* xu = (const unsigned int*)x;
                unsigned int u = xu[(size_t)row * 64 + lane];
                a0 = bf2f(u & 0xffff); a1 = bf2f(u >> 16);
                int j = beg;
                for (; j + 8 <= end; j += 8) {
                    unsigned int u0 = xu[(size_t)bucket[j] * 64 + lane];
                    unsigned int u1 = xu[(size_t)bucket[j + 1] * 64 + lane];
                    unsigned int u2 = xu[(size_t)bucket[j + 2] * 64 + lane];
                    unsigned int u3 = xu[(size_t)bucket[j + 3] * 64 + lane];
                    unsigned int u4 = xu[(size_t)bucket[j + 4] * 64 + lane];
                    unsigned int u5 = xu[(size_t)bucket[j + 5] * 64 + lane];
                    unsigned int u6 = xu[(size_t)bucket[j + 6] * 64 + lane];
                    unsigned int u7 = xu[(size_t)bucket[j + 7] * 64 + lane];
                    a0 += ((bf2f(u0 & 0xffff) + bf2f(u1 & 0xffff)) + (bf2f(u2 & 0xffff) + bf2f(u3 & 0xffff)))
                        + ((bf2f(u4 & 0xffff) + bf2f(u5 & 0xffff)) + (bf2f(u6 & 0xffff) + bf2f(u7 & 0xffff)));
                    a1 += ((bf2f(u0 >> 16) + bf2f(u1 >> 16)) + (bf2f(u2 >> 16) + bf2f(u3 >> 16)))
                        + ((bf2f(u4 >> 16) + bf2f(u5 >> 16)) + (bf2f(u6 >> 16) + bf2f(u7 >> 16)));
                }
                for (; j + 4 <= end; j += 4) {
                    unsigned int u0 = xu[(size_t)bucket[j] * 64 + lane];
                    unsigned int u1 = xu[(size_t)bucket[j + 1] * 64 + lane];
                    unsigned int u2 = xu[(size_t)bucket[j + 2] * 64 + lane];
                    unsigned int u3 = xu[(size_t)bucket[j + 3] * 64 + lane];
                    a0 += (bf2f(u0 & 0xffff) + bf2f(u1 & 0xffff)) + (bf2f(u2 & 0xffff) + bf2f(u3 & 0xffff));
                    a1 += (bf2f(u0 >> 16) + bf2f(u1 >> 16)) + (bf2f(u2 >> 16) + bf2f(u3 >> 16));
                }
                for (; j < end; j++) {
                    unsigned int n = xu[(size_t)bucket[j] * 64 + lane];
                    a0 += bf2f(n & 0xffff); a1 += bf2f(n >> 16);
                }
            }
        }
        // write bf16 pair into swizzled X tile: col c = 2*lane
        int c = lane * 2, chunk = c >> 3, off = c & 7;
        *(unsigned int*)(bufA + r * 128 + ((chunk ^ (r & 15)) * 8) + off) =
            (unsigned int)f2bf(a0) | ((unsigned int)f2bf(a1) << 16);
    }
    // ---- GEMM phase: 8 waves (4 row-groups x 2 col-groups), nb loop ----
    int wid = t >> 6;
    int wm = wid & 3, wn = wid >> 2;
    int quad = lane >> 4, l16 = lane & 15;
    for (int nb = 0; nb < 4; nb++) {
        // stage W1 tile for nb (2048 uint4)
#pragma unroll
        for (int i = 0; i < 4; i++) {
            int idx = t + i * 512;
            int rr = idx >> 4, chunk = idx & 15;
            *(uint4*)(bufW + rr * 128 + ((chunk ^ (rr & 15)) * 8)) =
                *(const uint4*)(w1t + (size_t)(nb * 128 + rr) * 128 + chunk * 8);
        }
        __syncthreads();   // W staged; first iter also publishes all gather writes + sred init
        f32x4 acc[2][4] = {};
#pragma unroll
        for (int ks = 0; ks < 4; ks++) {
            short8 af[2], bw[4];
#pragma unroll
            for (int mt = 0; mt < 2; mt++)
                af[mt] = *(const short8*)(bufA + (wm * 32 + mt * 16 + l16) * 128 + (((ks * 4 + quad) ^ l16) * 8));
#pragma unroll
            for (int nt = 0; nt < 4; nt++)
                bw[nt] = *(const short8*)(bufW + (wn * 64 + nt * 16 + l16) * 128 + (((ks * 4 + quad) ^ l16) * 8));
#pragma unroll
            for (int mt = 0; mt < 2; mt++)
#pragma unroll
                for (int nt = 0; nt < 4; nt++)
                    acc[mt][nt] = __builtin_amdgcn_mfma_f32_16x16x32_bf16(af[mt], bw[nt], acc[mt][nt], 0, 0, 0);
        }
        __syncthreads();   // MFMA bufW reads done; reuse bufW for h1 staging
        // epilogue: z = acc + b1 (raw), BN1 stats into sred, stage z row-major
#pragma unroll
        for (int nt = 0; nt < 4; nt++) {
            int n = wn * 64 + nt * 16 + l16;
            int n1 = nb * 128 + n;
            float bias = loadP(b1, n1, isf);
            float s = 0.f, ss = 0.f;
#pragma unroll
            for (int mt = 0; mt < 2; mt++) {
#pragma unroll
                for (int rg = 0; rg < 4; rg++) {
                    int Rl = wm * 32 + mt * 16 + quad * 4 + rg;
                    float z = acc[mt][nt][rg] + bias;
                    bufW[Rl * 128 + n] = f2bf(z);
                    if (m0 + Rl < N_NODES) { s += z; ss += z * z; }
                }
            }
            s += __shfl_xor(s, 16, 64); ss += __shfl_xor(ss, 16, 64);
            s += __shfl_xor(s, 32, 64); ss += __shfl_xor(ss, 32, 64);
            if (quad == 0) { atomicAdd(&sred[n], s); atomicAdd(&sred[128 + n], ss); }
        }
        __syncthreads();   // tile + sred complete
        // coalesced copy-out + stats flush + sred reset
#pragma unroll
        for (int i = 0; i < 4; i++) {
            int idx = t + i * 512;
            int rr = idx >> 4, seg = idx & 15;
            *(uint4*)(h1 + (size_t)(m0 + rr) * D_HID + nb * 128 + seg * 8) =
                *(const uint4*)(bufW + rr * 128 + seg * 8);
        }
        if (t < 256) {
            int n = t & 127;
            if (t < 128) atomicAdd(&sum1[nb * 128 + n], sred[n]);
            else         atomicAdd(&sumsq1[nb * 128 + n], sred[128 + n]);
            sred[t] = 0.f;
        }
        __syncthreads();   // copy-out reads + sred reset done before next nb overwrites bufW
    }
}

// ---- Gram: Gpart[b] = partial A^T A over this block's row tiles; colsum atomics ----
__global__ __launch_bounds__(256) void k_gram(const unsigned short* __restrict__ aggb,
                                              float* __restrict__ Gpart,
                                              float* __restrict__ colsum) {
    __shared__ unsigned short ldsT[128 * 64];   // [col][k], k-chunks XOR-swizzled, 16 KB
    int t = threadIdx.x;
    int wid = t >> 6, lane = t & 63;
    int wm = wid & 1, wn = wid >> 1;
    int quad = lane >> 4, l16 = lane & 15;
    f32x4 acc[4][4] = {};
    float cs = 0.f;
    int cscol = t & 127, cskh = t >> 7;
    for (int tile = blockIdx.x; tile < G_TILES; tile += G_BLOCKS) {
        __syncthreads();
        size_t rowbase = (size_t)tile * 64;
#pragma unroll
        for (int jj = 0; jj < 2; jj++) {
            int j = t + jj * 256;
            int c = j >> 5, rp = j & 31;          // cols c*8..+7, rows 2rp,2rp+1
            uint4 v0 = *(const uint4*)(aggb + (rowbase + 2 * rp) * 128 + c * 8);
            uint4 v1 = *(const uint4*)(aggb + (rowbase + 2 * rp + 1) * 128 + c * 8);
            const unsigned short* p0 = (const unsigned short*)&v0;
            const unsigned short* p1 = (const unsigned short*)&v1;
            int k = 2 * rp, kc = k >> 3, ko = k & 7;
#pragma unroll
            for (int e = 0; e < 8; e++) {
                int col = c * 8 + e;
                *(unsigned int*)(ldsT + col * 64 + ((kc ^ (col & 7)) * 8) + ko) =
                    (unsigned int)p0[e] | ((unsigned int)p1[e] << 16);
            }
        }
        __syncthreads();
#pragma unroll
        for (int ksub = 0; ksub < 2; ksub++) {
            short8 fa[4], fb[4];
#pragma unroll
            for (int mt = 0; mt < 4; mt++) {
                int col = wm * 64 + mt * 16 + l16;
                fa[mt] = *(const short8*)(ldsT + col * 64 + (((ksub * 4 + quad) ^ (col & 7)) * 8));
            }
#pragma unroll
            for (int nt = 0; nt < 4; nt++) {
                int col = wn * 64 + nt * 16 + l16;
                fb[nt] = *(const short8*)(ldsT + col * 64 + (((ksub * 4 + quad) ^ (col & 7)) * 8));
            }
#pragma unroll
            for (int mt = 0; mt < 4; mt++)
#pragma unroll
                for (int nt = 0; nt < 4; nt++)
                    acc[mt][nt] = __builtin_amdgcn_mfma_f32_16x16x32_bf16(fa[mt], fb[nt], acc[mt][nt], 0, 0, 0);
        }
        // colsum partial: thread handles (col, k-half)
#pragma unroll
        for (int kc = 0; kc < 4; kc++) {
            short8 v = *(const short8*)(ldsT + cscol * 64 + (((cskh * 4 + kc) ^ (cscol & 7)) * 8));
#pragma unroll
            for (int e = 0; e < 8; e++) cs += bf2f((unsigned short)v[e]);
        }
    }
    float* gp = Gpart + (size_t)blockIdx.x * 16384;
#pragma unroll
    for (int mt = 0; mt < 4; mt++)
#pragma unroll
        for (int nt = 0; nt < 4; nt++) {
            int m = wm * 64 + mt * 16 + quad * 4;
            int n = wn * 64 + nt * 16 + l16;
#pragma unroll
            for (int rg = 0; rg < 4; rg++)
                gp[(m + rg) * 128 + n] = acc[mt][nt][rg];
        }
    atomicAdd(&colsum[cscol], cs);
}

// ---- reduce Gpart -> G ----
__global__ void k_gred(const float* __restrict__ Gpart, float* __restrict__ G) {
    int i = blockIdx.x * 256 + threadIdx.x;     // 64 blocks -> 16384 threads
    float s = 0.f;
#pragma unroll 8
    for (int b = 0; b < G_BLOCKS; b++) s += Gpart[(size_t)b * 16384 + i];
    G[i] = s;
}

// ---- BN1 stats from Gram ----
__global__ __launch_bounds__(256) void k_bn1(const float* __restrict__ G,
                                             const float* __restrict__ colsum,
                                             const unsigned short* __restrict__ w1t,
                                             const void* __restrict__ b1,
                                             float* __restrict__ sum1,
                                             float* __restrict__ sumsq1,
                                             const int* __restrict__ flags) {
    int isf = flags[0];
    __shared__ float wsh[4][128];
    int t = threadIdx.x, wid = t >> 6, lane = t & 63;
    int n = blockIdx.x * 4 + wid;               // 128 blocks x 4 waves = 512 n
    unsigned int u = *(const unsigned int*)(w1t + (size_t)n * 128 + lane * 2);
    wsh[wid][lane * 2] = bf2f(u & 0xffff);
    wsh[wid][lane * 2 + 1] = bf2f(u >> 16);
    __syncthreads();
    const float* w = wsh[wid];
    const f32x4* g0 = (const f32x4*)(G + (size_t)lane * 128);
    const f32x4* g1 = (const f32x4*)(G + (size_t)(lane + 64) * 128);
    float t0 = 0.f, t1 = 0.f;
#pragma unroll 4
    for (int q4 = 0; q4 < 32; q4++) {
        f32x4 a = g0[q4], b = g1[q4];
        float w0 = w[q4 * 4], w1 = w[q4 * 4 + 1], w2 = w[q4 * 4 + 2], w3 = w[q4 * 4 + 3];
        t0 += a[0] * w0 + a[1] * w1 + a[2] * w2 + a[3] * w3;
        t1 += b[0] * w0 + b[1] * w1 + b[2] * w2 + b[3] * w3;
    }
    float sq = w[lane] * t0 + w[lane + 64] * t1;
    float s  = w[lane] * colsum[lane] + w[lane + 64] * colsum[lane + 64];
#pragma unroll
    for (int m = 1; m < 64; m <<= 1) {
        sq += __shfl_xor(sq, m, 64);
        s  += __shfl_xor(s, m, 64);
    }
    if (lane == 0) {
        float b = loadP(b1, n, isf);
        sum1[n]   = s + (float)N_NODES * b;
        sumsq1[n] = sq + 2.f * b * s + (float)N_NODES * b * b;
    }
}

// ---- MLP stage 1 (gram path, per chunk): h1c = relu(BN1(aggc @ W1 + b1)) ----
__global__ __launch_bounds__(256, 2) void k_mlp1(const unsigned short* __restrict__ aggc,
                                                 const unsigned short* __restrict__ w1t,
                                                 const void* __restrict__ b1,
                                                 const void* __restrict__ g1,
                                                 const void* __restrict__ bb1,
                                                 const float* __restrict__ sum1,
                                                 const float* __restrict__ sumsq1,
                                                 unsigned short* __restrict__ h1c,
                                                 const int* __restrict__ flags) {
    __shared__ unsigned short bufA[128 * 128];   // 32 KB: X tile, then output tile
    __shared__ unsigned short bufW[128 * 128];   // 32 KB: W1 tile
    int isf = flags[0];
    int t = threadIdx.x;
    int m0 = (blockIdx.x >> 2) * 128;            // chunk-relative row
    int nb = blockIdx.x & 3;
    int r = t >> 1, half = t & 1;
    int wid = t >> 6, lane = t & 63;
    int wm = wid & 1, wn = wid >> 1;
    int quad = lane >> 4, l16 = lane & 15;
#pragma unroll
    for (int i = 0; i < 8; i++) {
        int chunk = half * 8 + i;
        int sw = ((chunk ^ (r & 15)) * 8);
        *(uint4*)(bufA + r * 128 + sw) = *(const uint4*)(aggc + (size_t)(m0 + r) * 128 + chunk * 8);
        *(uint4*)(bufW + r * 128 + sw) = *(const uint4*)(w1t + (size_t)(nb * 128 + r) * 128 + chunk * 8);
    }
    __syncthreads();
    f32x4 acc[4][4] = {};
#pragma unroll
    for (int ks = 0; ks < 4; ks++) {
        short8 af[4], bw[4];
#pragma unroll
        for (int mt = 0; mt < 4; mt++)
            af[mt] = *(const short8*)(bufA + (wm * 64 + mt * 16 + l16) * 128 + (((ks * 4 + quad) ^ l16) * 8));
#pragma unroll
        for (int nt = 0; nt < 4; nt++)
            bw[nt] = *(const short8*)(bufW + (wn * 64 + nt * 16 + l16) * 128 + (((ks * 4 + quad) ^ l16) * 8));
#pragma unroll
        for (int mt = 0; mt < 4; mt++)
#pragma unroll
            for (int nt = 0; nt < 4; nt++)
                acc[mt][nt] = __builtin_amdgcn_mfma_f32_16x16x32_bf16(af[mt], bw[nt], acc[mt][nt], 0, 0, 0);
    }
    __syncthreads();   // all LDS reads done; bufA reused for output
#pragma unroll
    for (int nt = 0; nt < 4; nt++) {
        int nl = wn * 64 + nt * 16 + l16;
        int n1 = nb * 128 + nl;
        float mz = sum1[n1] * (1.f / N_NODES);
        float vz = sumsq1[n1] * (1.f / N_NODES) - mz * mz;
        float inv = rsqrtf(fmaxf(vz, 0.f) + 1e-5f);
        float A = loadP(g1, n1, isf) * inv;
        float C = loadP(bb1, n1, isf) - mz * A + loadP(b1, n1, isf) * A;
        int ccw = nl >> 3, cl = nl & 7;
#pragma unroll
        for (int mt = 0; mt < 4; mt++)
#pragma unroll
            for (int rg = 0; rg < 4; rg++) {
                int R = wm * 64 + mt * 16 + quad * 4 + rg;
                bufA[R * 128 + ((ccw ^ (R & 15)) * 8) + cl] = f2bf(fmaxf(acc[mt][nt][rg] * A + C, 0.f));
            }
    }
    __syncthreads();
#pragma unroll
    for (int i = 0; i < 8; i++) {
        int idx = t + i * 256;                   // 2048 uint4 = full 32 KB tile
        int rr = idx >> 4, chunk = idx & 15;
        *(uint4*)(h1c + (size_t)(m0 + rr) * D_HID + nb * 128 + chunk * 8) =
            *(const uint4*)(bufA + rr * 128 + ((chunk ^ (rr & 15)) * 8));
    }
}

// ---- MLP stage 1 (sep big-ws path): h1 = agg @ W1 + b1 RAW, BN1 stats fused ----
__global__ __launch_bounds__(256, 2) void k_mlp1r(const unsigned short* __restrict__ aggb,
                                                  const unsigned short* __restrict__ w1t,
                                                  const void* __restrict__ b1,
                                                  unsigned short* __restrict__ h1,
                                                  float* __restrict__ sum1,
                                                  float* __restrict__ sumsq1,
                                                  const int* __restrict__ flags) {
    __shared__ unsigned short bufA[128 * 128];
    __shared__ unsigned short bufW[128 * 128];
    __shared__ float sred[256];
    int isf = flags[0];
    int t = threadIdx.x;
    int m0 = (blockIdx.x >> 2) * 128;
    int nb = blockIdx.x & 3;
    int r = t >> 1, half = t & 1;
    int wid = t >> 6, lane = t & 63;
    int wm = wid & 1, wn = wid >> 1;
    int quad = lane >> 4, l16 = lane & 15;
    sred[t] = 0.f;
#pragma unroll
    for (int i = 0; i < 8; i++) {
        int chunk = half * 8 + i;
        int sw = ((chunk ^ (r & 15)) * 8);
        *(uint4*)(bufA + r * 128 + sw) = *(const uint4*)(aggb + (size_t)(m0 + r) * 128 + chunk * 8);
        *(uint4*)(bufW + r * 128 + sw) = *(const uint4*)(w1t + (size_t)(nb * 128 + r) * 128 + chunk * 8);
    }
    __syncthreads();
    f32x4 acc[4][4] = {};
#pragma unroll
    for (int ks = 0; ks < 4; ks++) {
        short8 af[4], bw[4];
#pragma unroll
        for (int mt = 0; mt < 4; mt++)
            af[mt] = *(const short8*)(bufA + (wm * 64 + mt * 16 + l16) * 128 + (((ks * 4 + quad) ^ l16) * 8));
#pragma unroll
        for (int nt = 0; nt < 4; nt++)
            bw[nt] = *(const short8*)(bufW + (wn * 64 + nt * 16 + l16) * 128 + (((ks * 4 + quad) ^ l16) * 8));
#pragma unroll
        for (int mt = 0; mt < 4; mt++)
#pragma unroll
            for (int nt = 0; nt < 4; nt++)
                acc[mt][nt] = __builtin_amdgcn_mfma_f32_16x16x32_bf16(af[mt], bw[nt], acc[mt][nt], 0, 0, 0);
    }
    __syncthreads();
#pragma unroll
    for (int nt = 0; nt < 4; nt++) {
        int nl = wn * 64 + nt * 16 + l16;
        int n1 = nb * 128 + nl;
        float bias = loadP(b1, n1, isf);
        int ccw = nl >> 3, cl = nl & 7;
        float s = 0.f, ss = 0.f;
#pragma unroll
        for (int mt = 0; mt < 4; mt++)
#pragma unroll
            for (int rg = 0; rg < 4; rg++) {
                int R = wm * 64 + mt * 16 + quad * 4 + rg;
                float z = acc[mt][nt][rg] + bias;
                bufA[R * 128 + ((ccw ^ (R & 15)) * 8) + cl] = f2bf(z);
                if (m0 + R < N_NODES) { s += z; ss += z * z; }
            }
        s += __shfl_xor(s, 16, 64); ss += __shfl_xor(ss, 16, 64);
        s += __shfl_xor(s, 32, 64); ss += __shfl_xor(ss, 32, 64);
        if (quad == 0) { atomicAdd(&sred[nl], s); atomicAdd(&sred[128 + nl], ss); }
    }
    __syncthreads();
#pragma unroll
    for (int i = 0; i < 8; i++) {
        int idx = t + i * 256;
        int rr = idx >> 4, chunk = idx & 15;
        *(uint4*)(h1 + (size_t)(m0 + rr) * D_HID + nb * 128 + chunk * 8) =
            *(const uint4*)(bufA + rr * 128 + ((chunk ^ (rr & 15)) * 8));
    }
    if (t < 128)      atomicAdd(&sum1[nb * 128 + t], sred[t]);
    else              atomicAdd(&sumsq1[nb * 128 + (t - 128)], sred[t]);
}

// ---- MLP stage 2 (gram path, per chunk): h2c = h1c @ W2 + b2, BN2 stats fused ----
__global__ __launch_bounds__(256, 3) void k_mlp2(const unsigned short* __restrict__ h1c,
                                                 const unsigned short* __restrict__ w2t,
                                                 const void* __restrict__ b2,
                                                 unsigned short* __restrict__ h2c,
                                                 float* __restrict__ sum2,
                                                 float* __restrict__ sumsq2,
                                                 const int* __restrict__ flags,
                                                 int roff) {
    __shared__ unsigned short bufA[64 * 128];
    __shared__ unsigned short bufW[128 * 128];
    __shared__ float sred[256];
    int isf = flags[0];
    int t = threadIdx.x;
    int m0 = blockIdx.x * 64;
    int rw = t >> 1, halfw = t & 1;
    int wid = t >> 6, lane = t & 63;
    int wm = wid & 1, wn = wid >> 1;
    int quad = lane >> 4, l16 = lane & 15;
    sred[t] = 0.f;
    f32x4 acc[2][4] = {};
    for (int kb = 0; kb < 4; kb++) {
        __syncthreads();
#pragma unroll
        for (int i = 0; i < 4; i++) {
            int idx = t + i * 256;
            int rr = idx >> 4, chunk = idx & 15;
            *(uint4*)(bufA + rr * 128 + ((chunk ^ (rr & 15)) * 8)) =
                *(const uint4*)(h1c + (size_t)(m0 + rr) * D_HID + kb * 128 + chunk * 8);
        }
#pragma unroll
        for (int i = 0; i < 8; i++) {
            int chunk = halfw * 8 + i;
            *(uint4*)(bufW + rw * 128 + ((chunk ^ (rw & 15)) * 8)) =
                *(const uint4*)(w2t + (size_t)rw * D_HID + kb * 128 + chunk * 8);
        }
        __syncthreads();
#pragma unroll
        for (int ks = 0; ks < 4; ks++) {
            short8 af[2], bw[4];
#pragma unroll
            for (int mt = 0; mt < 2; mt++)
                af[mt] = *(const short8*)(bufA + (wm * 32 + mt * 16 + l16) * 128 + (((ks * 4 + quad) ^ l16) * 8));
#pragma unroll
            for (int nt = 0; nt < 4; nt++)
                bw[nt] = *(const short8*)(bufW + (wn * 64 + nt * 16 + l16) * 128 + (((ks * 4 + quad) ^ l16) * 8));
#pragma unroll
            for (int mt = 0; mt < 2; mt++)
#pragma unroll
                for (int nt = 0; nt < 4; nt++)
                    acc[mt][nt] = __builtin_amdgcn_mfma_f32_16x16x32_bf16(af[mt], bw[nt], acc[mt][nt], 0, 0, 0);
        }
    }
    __syncthreads();
#pragma unroll
    for (int nt = 0; nt < 4; nt++) {
        int n = wn * 64 + nt * 16 + l16;
        float bias = loadP(b2, n, isf);
        float s = 0.f, ss = 0.f;
#pragma unroll
        for (int mt = 0; mt < 2; mt++) {
            int Rl = wm * 32 + mt * 16 + quad * 4;
#pragma unroll
            for (int rg = 0; rg < 4; rg++) {
                float z = acc[mt][nt][rg] + bias;
                bufW[(Rl + rg) * 128 + n] = f2bf(z);
                if (roff + m0 + Rl + rg < N_NODES) { s += z; ss += z * z; }
            }
        }
        s += __shfl_xor(s, 16, 64); ss += __shfl_xor(ss, 16, 64);
        s += __shfl_xor(s, 32, 64); ss += __shfl_xor(ss, 32, 64);
        if (quad == 0) { atomicAdd(&sred[n], s); atomicAdd(&sred[128 + n], ss); }
    }
    __syncthreads();
#pragma unroll
    for (int i = 0; i < 4; i++) {
        int idx = t + i * 256;
        int rr = idx >> 4, seg = idx & 15;
        *(uint4*)(h2c + (size_t)(m0 + rr) * D_IN + seg * 8) = *(const uint4*)(bufW + rr * 128 + seg * 8);
    }
    {
        int n = t & 127;
        if (t < 128) atomicAdd(&sum2[n], sred[n]);
        else         atomicAdd(&sumsq2[n], sred[128 + n]);
    }
}

// ---- MLP stage 2 (big-ws path): BM=128, 8 waves; BN1+ReLU on staging ----
__global__ __launch_bounds__(512, 4) void k_mlp2b(const unsigned short* __restrict__ h1,
                                                  const unsigned short* __restrict__ w2t,
                                                  const void* __restrict__ b2,
                                                  const void* __restrict__ g1,
                                                  const void* __restrict__ bb1,
                                                  const float* __restrict__ sum1,
                                                  const float* __restrict__ sumsq1,
                                                  unsigned short* __restrict__ h2,
                                                  float* __restrict__ sum2,
                                                  float* __restrict__ sumsq2,
                                                  const int* __restrict__ flags) {
    __shared__ unsigned short bufA[128 * 128];   // 32 KB: relu(BN1(h1)) K-slice
    __shared__ unsigned short bufW[128 * 128];   // 32 KB: w2t K-slice / h2 staging
    __shared__ float sred[256];
    __shared__ __align__(16) float bnA[512];
    __shared__ __align__(16) float bnC[512];
    int isf = flags[0];
    int t = threadIdx.x;
    int m0 = blockIdx.x * 128;
    int wid = t >> 6, lane = t & 63;
    int wm = wid & 3, wn = wid >> 2;             // 4 row-groups x 2 col-groups
    int quad = lane >> 4, l16 = lane & 15;
    int chunkT = t & 15;                         // i-invariant column chunk
    if (t < 256) sred[t] = 0.f;
    if (t < 512) {
        float mz = sum1[t] * (1.f / N_NODES);
        float vz = sumsq1[t] * (1.f / N_NODES) - mz * mz;
        float inv = rsqrtf(fmaxf(vz, 0.f) + 1e-5f);
        float A = loadP(g1, t, isf) * inv;
        bnA[t] = A;
        bnC[t] = loadP(bb1, t, isf) - mz * A;    // b1 already inside raw h1
    }
    f32x4 acc[2][4] = {};
    for (int kb = 0; kb < 4; kb++) {
        __syncthreads();   // first iter covers bnA/bnC/sred init; later: prev LDS reads done
        f32x4 A0 = *(const f32x4*)(bnA + kb * 128 + chunkT * 8);
        f32x4 A1 = *(const f32x4*)(bnA + kb * 128 + chunkT * 8 + 4);
        f32x4 C0 = *(const f32x4*)(bnC + kb * 128 + chunkT * 8);
        f32x4 C1 = *(const f32x4*)(bnC + kb * 128 + chunkT * 8 + 4);
#pragma unroll
        for (int i = 0; i < 4; i++) {
            int idx = t + i * 512;
            int rr = idx >> 4;
            uint4 v = *(const uint4*)(h1 + (size_t)(m0 + rr) * D_HID + kb * 128 + chunkT * 8);
            const unsigned short* pv = (const unsigned short*)&v;
            unsigned short o[8];
            o[0] = f2bf(fmaxf(bf2f(pv[0]) * A0[0] + C0[0], 0.f));
            o[1] = f2bf(fmaxf(bf2f(pv[1]) * A0[1] + C0[1], 0.f));
            o[2] = f2bf(fmaxf(bf2f(pv[2]) * A0[2] + C0[2], 0.f));
            o[3] = f2bf(fmaxf(bf2f(pv[3]) * A0[3] + C0[3], 0.f));
            o[4] = f2bf(fmaxf(bf2f(pv[4]) * A1[0] + C1[0], 0.f));
            o[5] = f2bf(fmaxf(bf2f(pv[5]) * A1[1] + C1[1], 0.f));
            o[6] = f2bf(fmaxf(bf2f(pv[6]) * A1[2] + C1[2], 0.f));
            o[7] = f2bf(fmaxf(bf2f(pv[7]) * A1[3] + C1[3], 0.f));
            *(uint4*)(bufA + rr * 128 + ((chunkT ^ (rr & 15)) * 8)) = *(const uint4*)o;
        }
#pragma unroll
        for (int i = 0; i < 4; i++) {
            int idx = t + i * 512;
            int rr = idx >> 4;
            *(uint4*)(bufW + rr * 128 + ((chunkT ^ (rr & 15)) * 8)) =
                *(const uint4*)(w2t + (size_t)rr * D_HID + kb * 128 + chunkT * 8);
        }
        __syncthreads();
#pragma unroll
        for (int ks = 0; ks < 4; ks++) {
            short8 af[2], bw[4];
#pragma unroll
            for (int mt = 0; mt < 2; mt++)
                af[mt] = *(const short8*)(bufA + (wm * 32 + mt * 16 + l16) * 128 + (((ks * 4 + quad) ^ l16) * 8));
#pragma unroll
            for (int nt = 0; nt < 4; nt++)
                bw[nt] = *(const short8*)(bufW + (wn * 64 + nt * 16 + l16) * 128 + (((ks * 4 + quad) ^ l16) * 8));
#pragma unroll
            for (int mt = 0; mt < 2; mt++)
#pragma unroll
                for (int nt = 0; nt < 4; nt++)
                    acc[mt][nt] = __builtin_amdgcn_mfma_f32_16x16x32_bf16(af[mt], bw[nt], acc[mt][nt], 0, 0, 0);
        }
    }
    __syncthreads();       // last LDS reads done; bufW reused for h2 staging
#pragma unroll
    for (int nt = 0; nt < 4; nt++) {
        int n = wn * 64 + nt * 16 + l16;
        float bias = loadP(b2, n, isf);
        float s = 0.f, ss = 0.f;
#pragma unroll
        for (int mt = 0; mt < 2; mt++) {
            int Rl = wm * 32 + mt * 16 + quad * 4;
#pragma unroll
            for (int rg = 0; rg < 4; rg++) {
                float z = acc[mt][nt][rg] + bias;
                bufW[(Rl + rg) * 128 + n] = f2bf(z);
                if (m0 + Rl + rg < N_NODES) { s += z; ss += z * z; }
            }
        }
        s += __shfl_xor(s, 16, 64); ss += __shfl_xor(ss, 16, 64);
        s += __shfl_xor(s, 32, 64); ss += __shfl_xor(ss, 32, 64);
        if (quad == 0) { atomicAdd(&sred[n], s); atomicAdd(&sred[128 + n], ss); }
    }
    __syncthreads();
#pragma unroll
    for (int i = 0; i < 4; i++) {
        int idx = t + i * 512;                   // 2048 uint4 = 32 KB (128x128 tile)
        int rr = idx >> 4, seg = idx & 15;
        *(uint4*)(h2 + (size_t)(m0 + rr) * D_IN + seg * 8) = *(const uint4*)(bufW + rr * 128 + seg * 8);
    }
    if (t < 256) {
        int n = t & 127;
        if (t < 128) atomicAdd(&sum2[n], sred[n]);
        else         atomicAdd(&sumsq2[n], sred[128 + n]);
    }
}

// ---- BN2 + ReLU + residual + LayerNorm -> out (h2 bf16 input) ----
__global__ __launch_bounds__(256) void k_final(const unsigned short* __restrict__ h2,
                                               const void* __restrict__ x,
                                               const float* __restrict__ sum2,
                                               const float* __restrict__ sumsq2,
                                               const void* __restrict__ g2,
                                               const void* __restrict__ bb2,
                                               const void* __restrict__ lng,
                                               const void* __restrict__ lnb,
                                               void* __restrict__ out,
                                               const int* __restrict__ flags) {
    int isf = flags[0];
    __shared__ float a2s[D_IN], c2s[D_IN];
    int t = threadIdx.x;
    if (t < D_IN) {
        float m = sum2[t] * (1.f / N_NODES);
        float v = sumsq2[t] * (1.f / N_NODES) - m * m;
        float inv = rsqrtf(fmaxf(v, 0.f) + 1e-5f);
        float a = loadP(g2, t, isf) * inv;
        a2s[t] = a;
        c2s[t] = loadP(bb2, t, isf) - m * a;
    }
    __syncthreads();
    int w = t >> 6, lane = t & 63;
    int row = blockIdx.x * 4 + w;
    if (row >= N_NODES) return;
    size_t base = (size_t)row * D_IN;
    int c0 = lane * 2, c1 = lane * 2 + 1;
    unsigned int hu = ((const unsigned int*)h2)[base / 2 + lane];
    float x0, x1;
    if (isf) {
        float2 xv = *((const float2*)x + base / 2 + lane);
        x0 = xv.x; x1 = xv.y;
    } else {
        unsigned int xu = ((const unsigned int*)x)[base / 2 + lane];
        x0 = bf2f(xu & 0xffff); x1 = bf2f(xu >> 16);
    }
    float o0 = fmaxf(a2s[c0] * bf2f(hu & 0xffff) + c2s[c0], 0.f) + x0;
    float o1 = fmaxf(a2s[c1] * bf2f(hu >> 16) + c2s[c1], 0.f) + x1;
    float s = o0 + o1, ss = o0 * o0 + o1 * o1;
#pragma unroll
    for (int m = 1; m < 64; m <<= 1) {
        s += __shfl_xor(s, m, 64);
        ss += __shfl_xor(ss, m, 64);
    }
    float mean = s * (1.f / D_IN);
    float var = ss * (1.f / D_IN) - mean * mean;
    float inv = rsqrtf(fmaxf(var, 0.f) + 1e-5f);
    float r0 = (o0 - mean) * inv * loadP(lng, c0, isf) + loadP(lnb, c0, isf);
    float r1 = (o1 - mean) * inv * loadP(lng, c1, isf) + loadP(lnb, c1, isf);
    if (isf) {
        *((float2*)out + base / 2 + lane) = make_float2(r0, r1);
    } else {
        ((unsigned int*)out)[base / 2 + lane] = (unsigned int)f2bf(r0) | ((unsigned int)f2bf(r1) << 16);
    }
}

extern "C" void kernel_launch(void* const* d_in, const int* in_sizes, int n_in,
                              void* d_out, int out_size, void* d_ws, size_t ws_size,
                              hipStream_t stream) {
    const void* x    = d_in[0];
    const int*  ei   = (const int*)d_in[1];
    const void* W1   = d_in[2];
    const void* b1   = d_in[3];
    const void* bn1g = d_in[4];
    const void* bn1b = d_in[5];
    const void* W2   = d_in[6];
    const void* b2   = d_in[7];
    const void* bn2g = d_in[8];
    const void* bn2b = d_in[9];
    const void* lng  = d_in[10];
    const void* lnb  = d_in[11];

    char* ws = (char*)d_ws;
    float* stats   = (float*)ws;                      // 1408 f32
    float* sum1    = stats;
    float* sumsq1  = stats + 512;
    float* sum2    = stats + 1024;
    float* sumsq2  = stats + 1152;
    float* colsum  = stats + 1280;
    int*   flags   = (int*)(ws + 5632);
    int*   partials= (int*)(ws + 5696);
    int*   rowptr  = (int*)(ws + 8192);               // 50001 ints
    int*   cursor  = (int*)(ws + 208256);             // 50000 ints
    unsigned short* w1t = (unsigned short*)(ws + 408320);   // [512][128] bf16
    unsigned short* w2t = (unsigned short*)(ws + 539392);   // [128][512] bf16
    float* G       = (float*)(ws + 670464);           // 128x128 f32 -> ends 736000
    unsigned short* agg = (unsigned short*)(ws + 736000);   // NPAD*128 bf16 -> ends 13548288; reused as h2
    unsigned short* h2  = agg;
    int*   bucket  = (int*)(ws + 13548288);           // 800000 ints -> ends 16748288
    float* Gpart   = (float*)(ws + 16748288);         // 256 x 16384 f32 (gram path)
    unsigned short* h1sep  = (unsigned short*)(ws + 13548288); // sep path: overlays bucket (dead)
    unsigned short* h1fuse = (unsigned short*)(ws + 16748288); // fused path: after live bucket

    k_init<<<202, 256, 0, stream>>>(x, ei, stats, cursor, flags);
    k_prep<<<512 + 8 * FILL_SUB, 256, 0, stream>>>(W1, W2, w1t, w2t, ei, cursor, flags);
    k_scan_block<<<SCAN_NB, 256, 0, stream>>>(cursor, rowptr, partials);
    k_scan_add<<<SCAN_NB, 256, 0, stream>>>(rowptr, cursor, partials);
    k_fill<<<8 * FILL_SUB, 256, 0, stream>>>(ei, cursor, bucket, flags);

    if ((long long)ws_size >= H1_FUSED_NEED) {
        // fused path: gather+GEMM1 in one kernel (overlap + no agg round-trip)
        k_gmlp1<<<NTILES, 512, 0, stream>>>(rowptr, bucket, x, w1t, b1, h1fuse, sum1, sumsq1, flags);
        k_mlp2b<<<NTILES, 512, 0, stream>>>(h1fuse, w2t, b2, bn1g, bn1b, sum1, sumsq1,
                                            h2, sum2, sumsq2, flags);
    } else if ((long long)ws_size >= H1_SEP_NEED) {
        k_gather<<<NPAD / 4, 256, 0, stream>>>(rowptr, bucket, x, agg, flags);
        k_mlp1r<<<NTILES * 4, 256, 0, stream>>>(agg, w1t, b1, h1sep, sum1, sumsq1, flags);
        k_mlp2b<<<NTILES, 512, 0, stream>>>(h1sep, w2t, b2, bn1g, bn1b, sum1, sumsq1,
                                            h2, sum2, sumsq2, flags);
    } else {
        k_gather<<<NPAD / 4, 256, 0, stream>>>(rowptr, bucket, x, agg, flags);
        k_gram<<<G_BLOCKS, 256, 0, stream>>>(agg, Gpart, colsum);
        k_gred<<<64, 256, 0, stream>>>(Gpart, G);
        k_bn1<<<128, 256, 0, stream>>>(G, colsum, w1t, b1, sum1, sumsq1, flags);
        long long avail = (long long)ws_size - 13548288LL;
        int max_tiles = (avail > 0) ? (int)(avail / 131072LL) : 1;
        if (max_tiles < 1)  max_tiles = 1;
        if (max_tiles > NTILES) max_tiles = NTILES;
        int nch = (NTILES + max_tiles - 1) / max_tiles;
        int per = (NTILES + nch - 1) / nch;
        for (int done = 0; done < NTILES; done += per) {
            int nt = NTILES - done;
            if (nt > per) nt = per;
            const unsigned short* aggc = agg + (size_t)done * 128 * 128;
            unsigned short* h2c = h2 + (size_t)done * 128 * 128;
            k_mlp1<<<nt * 4, 256, 0, stream>>>(aggc, w1t, b1, bn1g, bn1b, sum1, sumsq1, h1sep, flags);
            k_mlp2<<<nt * 2, 256, 0, stream>>>(h1sep, w2t, b2, h2c, sum2, sumsq2, flags, done * 128);
        }
    }

    k_final<<<(N_NODES + 3) / 4, 256, 0, stream>>>(h2, x, sum2, sumsq2, bn2g, bn2b, lng, lnb, d_out, flags);
}